// Round 17
// baseline (490.666 us; speedup 1.0000x reference)
//
#include <hip/hip_runtime.h>
#include <stdint.h>

typedef unsigned short u16;
typedef unsigned int u32;
typedef unsigned long long u64;
typedef __attribute__((ext_vector_type(8))) short short8;
typedef __attribute__((ext_vector_type(4))) float f32x4;

#define BSZ 4
#define NPT 2048
#define EMB 128
#define PH  64
#define AH  512
#define KNB 16

__device__ __forceinline__ u16 f2bf(float f) {
  union { float f; u32 u; } v; v.f = f;
  u32 r = (v.u >> 16) & 1u;
  v.u += 0x7fffu + r;
  return (u16)(v.u >> 16);
}
__device__ __forceinline__ float bf2f(u16 x) {
  union { u32 u; float f; } v; v.u = ((u32)x) << 16; return v.f;
}

// ---------------------------------------------------------------- transpose
__global__ __launch_bounds__(256) void k_transpose(
    const float* wq, const float* wk, const float* wv, const float* p2,
    const float* a1, const float* a2, const float* wo,
    u16* wqT, u16* wkT, u16* wvT, u16* p2T, u16* a1T, u16* a2T, u16* woT) {
  const float* src; u16* dst; int K, Nn;
  switch (blockIdx.x) {
    case 0: src = wq; dst = wqT; K = 128; Nn = 128; break;
    case 1: src = wk; dst = wkT; K = 128; Nn = 128; break;
    case 2: src = wv; dst = wvT; K = 128; Nn = 128; break;
    case 3: src = p2; dst = p2T; K = 64;  Nn = 128; break;
    case 4: src = a1; dst = a1T; K = 128; Nn = 512; break;
    case 5: src = a2; dst = a2T; K = 512; Nn = 128; break;
    default: src = wo; dst = woT; K = 128; Nn = 128; break;
  }
  for (int n = threadIdx.x; n < Nn; n += 256) {
    for (int k0 = 0; k0 < K; k0 += 8) {
      short8 vv;
      #pragma unroll
      for (int t = 0; t < 8; ++t)
        vv[t] = (short)f2bf(src[(k0 + t) * Nn + n]);
      *(short8*)(dst + n * K + k0) = vv;
    }
  }
}

// ---------------------------------------------------------------- knn
// Passing r13 version, unchanged. CURSE LOG: r4/r5/r9 restructures of the
// extraction loop all produced identical wrong output (absmax 0.71875) —
// only this r2 idiom passes; scheduling/memory-source changes at most.
__device__ __forceinline__ u32 f2sort(float f) {
  union { float f; u32 u; } v; v.f = f;
  return v.u ^ ((v.u >> 31) ? 0xFFFFFFFFu : 0x80000000u);
}

__global__ __launch_bounds__(256) void k_knn(const float* __restrict__ can,
                                             int* __restrict__ idx_out) {
  __shared__ float dists[4][NPT];
  int b = blockIdx.x >> 8;
  int qblk = blockIdx.x & 255;
  const float* cb = can + (size_t)b * NPT * 3;
  int wave = threadIdx.x >> 6, lane = threadIdx.x & 63;
  float* dw = dists[wave];
  #pragma unroll 1
  for (int t = 0; t < 2; ++t) {
    int i = qblk * 8 + wave * 2 + t;
    float xi = cb[i * 3 + 0], yi = cb[i * 3 + 1], zi = cb[i * 3 + 2];
    float sqi = __fadd_rn(__fadd_rn(__fmul_rn(xi, xi), __fmul_rn(yi, yi)),
                          __fmul_rn(zi, zi));
    u64 lmin = ~0ull;
    #pragma unroll 4
    for (int c = 0; c < NPT / 64; ++c) {
      int j = c * 64 + lane;
      const float* pj = cb + j * 3;
      float xj = pj[0], yj = pj[1], zj = pj[2];
      float sqj = __fadd_rn(__fadd_rn(__fmul_rn(xj, xj), __fmul_rn(yj, yj)),
                            __fmul_rn(zj, zj));
      float nn = __fadd_rn(__fadd_rn(__fmul_rn(xi, xj), __fmul_rn(yi, yj)),
                           __fmul_rn(zi, zj));
      float dist = __fadd_rn(__fsub_rn(sqi, __fmul_rn(2.0f, nn)), sqj);
      dw[j] = dist;
      u64 key = (((u64)f2sort(dist)) << 32) | (u32)j;
      lmin = key < lmin ? key : lmin;
    }
    #pragma unroll 1
    for (int r = 0; r < KNB; ++r) {
      u64 g = lmin;
      #pragma unroll
      for (int off = 32; off > 0; off >>= 1) {
        u64 o = __shfl_xor(g, off);
        g = o < g ? o : g;
      }
      int jw = (int)(u32)(g & 0xffffffffull);
      if (lane == 0) idx_out[((size_t)b * NPT + i) * KNB + r] = jw;
      if ((jw & 63) == lane) {
        union { u32 u; float f; } inf; inf.u = 0x7f800000u;
        dw[jw] = inf.f;
        lmin = ~0ull;
        #pragma unroll
        for (int c = 0; c < NPT / 64; ++c) {
          int j = c * 64 + lane;
          u64 key = (((u64)f2sort(dw[j])) << 32) | (u32)j;
          lmin = key < lmin ? key : lmin;
        }
      }
    }
  }
}

// ---------------------------------------------------------------- qkv
// pv[point][col] = bf16(q@wq - k@wk) | bf16(v@wv)<<16 (one gather stream).
__device__ __forceinline__ void qkv_gemm(const u16* At, const u16* wT,
                                         int colbase, int fm, int quad,
                                         f32x4 acc[2][4]) {
  #pragma unroll
  for (int tn = 0; tn < 2; ++tn)
    #pragma unroll
    for (int tm = 0; tm < 4; ++tm) acc[tn][tm] = (f32x4){0.f, 0.f, 0.f, 0.f};
  #pragma unroll
  for (int ks = 0; ks < 4; ++ks) {
    int k0 = ks * 32 + quad * 8;
    short8 bfr0 = *(const short8*)(wT + (colbase + fm) * 128 + k0);
    short8 bfr1 = *(const short8*)(wT + (colbase + 16 + fm) * 128 + k0);
    #pragma unroll
    for (int tm = 0; tm < 4; ++tm) {
      short8 afr = *(const short8*)(At + (tm * 16 + fm) * 136 + k0);
      acc[0][tm] = __builtin_amdgcn_mfma_f32_16x16x32_bf16(afr, bfr0, acc[0][tm], 0, 0, 0);
      acc[1][tm] = __builtin_amdgcn_mfma_f32_16x16x32_bf16(afr, bfr1, acc[1][tm], 0, 0, 0);
    }
  }
}

__device__ __forceinline__ void qkv_stage(u16* At, const float* src, int rbase, int tid) {
  #pragma unroll
  for (int rep = 0; rep < 4; ++rep) {
    int linear = tid + 256 * rep;
    int row = linear >> 4;
    int c16 = linear & 15;
    const float* sp = src + (size_t)(rbase + row) * 128 + c16 * 8;
    f32x4 a = *(const f32x4*)(sp);
    f32x4 b = *(const f32x4*)(sp + 4);
    short8 vv;
    vv[0] = (short)f2bf(a[0]); vv[1] = (short)f2bf(a[1]);
    vv[2] = (short)f2bf(a[2]); vv[3] = (short)f2bf(a[3]);
    vv[4] = (short)f2bf(b[0]); vv[5] = (short)f2bf(b[1]);
    vv[6] = (short)f2bf(b[2]); vv[7] = (short)f2bf(b[3]);
    *(short8*)(At + row * 136 + c16 * 8) = vv;
  }
}

__global__ __launch_bounds__(256) void k_qkv(
    const float* __restrict__ query, const float* __restrict__ key,
    const float* __restrict__ value,
    const u16* __restrict__ wqT, const u16* __restrict__ wkT,
    const u16* __restrict__ wvT,
    u32* __restrict__ pv_out) {
  __shared__ __align__(16) u16 At[64 * 136];
  int tid = threadIdx.x;
  int rbase = blockIdx.x * 64;
  int lane = tid & 63, wave = tid >> 6;
  int fm = lane & 15, quad = lane >> 4;
  int colbase = wave * 32;
  f32x4 accq[2][4], acck[2][4];

  qkv_stage(At, query, rbase, tid);
  __syncthreads();
  qkv_gemm(At, wqT, colbase, fm, quad, accq);
  __syncthreads();
  qkv_stage(At, key, rbase, tid);
  __syncthreads();
  qkv_gemm(At, wkT, colbase, fm, quad, acck);
  u32 qk2[4][4];
  #pragma unroll
  for (int tm = 0; tm < 4; ++tm)
    #pragma unroll
    for (int r = 0; r < 4; ++r)
      qk2[tm][r] = (u32)f2bf(accq[0][tm][r] - acck[0][tm][r]) |
                   (((u32)f2bf(accq[1][tm][r] - acck[1][tm][r])) << 16);
  __syncthreads();
  qkv_stage(At, value, rbase, tid);
  __syncthreads();
  qkv_gemm(At, wvT, colbase, fm, quad, accq);
  #pragma unroll
  for (int tn = 0; tn < 2; ++tn) {
    int col = colbase + tn * 16 + fm;
    #pragma unroll
    for (int tm = 0; tm < 4; ++tm)
      #pragma unroll
      for (int r = 0; r < 4; ++r) {
        int row = tm * 16 + quad * 4 + r;
        u32 qkb = tn == 0 ? (qk2[tm][r] & 0xffffu) : (qk2[tm][r] >> 16);
        u32 pack = qkb | (((u32)f2bf(accq[tn][tm][r])) << 16);
        pv_out[(size_t)(rbase + row) * 128 + col] = pack;
      }
  }
}

// ---------------------------------------------------------------- fused attention
// r17: WAVE-PARALLEL block. Each wave owns ONE query (16 rows): Xt/R1/H are
// wave-private LDS slices (same-wave write->read ordered by lgkmcnt — the
// verified per-wave LDS-transpose idiom), softmax reduces via fm-shuffles,
// neighbor reduction via quad-shuffles. Barriers: 10 -> 2 (Idx staging +
// pre-output-GEMM join). MFMA count per wave unchanged (272: 1 tm x 8 tn).
// Cost: each wave reads all 512 a1 cols -> a1/a2 L2 traffic x4 (L2-resident).
#define XT_LD 136

__global__ __launch_bounds__(256, 3) void k_attn(
    const float* __restrict__ can,
    const u32* __restrict__ pv_g,
    const int* __restrict__ idx_g,
    const float* __restrict__ p1, const float* __restrict__ pb1,
    const u16* __restrict__ p2T, const float* __restrict__ pb2,
    const u16* __restrict__ a1T, const float* __restrict__ ab1,
    const u16* __restrict__ a2T, const float* __restrict__ ab2,
    const u16* __restrict__ woT, const float* __restrict__ bo,
    float* __restrict__ out) {
  __shared__ __align__(16) char smem[37120];
  u16* Xt = (u16*)(smem);               // [64][136] bf16 (16 rows per wave)
  u16* Hs = (u16*)(smem + 17408);       // [64][136] bf16 (16 rows per wave)
  u16* R1 = (u16*)(smem + 17408);       // [64][72] bf16 (overlay, dead pre-H)
  float* Agg = (float*)(smem + 34816);  // [4][128] f32
  int* Idx = (int*)(smem + 36864);      // [64]

  const int b = blockIdx.x >> 9;
  const int qbase = (blockIdx.x & 511) * 4;
  const int tid = threadIdx.x;
  const int lane = tid & 63, w = tid >> 6;
  const int fm = lane & 15, quad = lane >> 4;

  if (tid < 64) Idx[tid] = idx_g[((size_t)b * NPT + qbase) * KNB + tid];
  __syncthreads();

  // neighbor indices for this lane's rows (row = w*16 + quad*4 + r)
  int jreg[4];
  #pragma unroll
  for (int r = 0; r < 4; ++r) jreg[r] = Idx[w * 16 + quad * 4 + r];

  // prefetch all 32 pv gathers; latency hides under phase 1 + phase-2 MFMA
  u32 pvld[8][4];
  #pragma unroll
  for (int tn = 0; tn < 8; ++tn) {
    int col = tn * 16 + fm;
    #pragma unroll
    for (int r = 0; r < 4; ++r)
      pvld[tn][r] = pv_g[((size_t)b * NPT + jreg[r]) * EMB + col];
  }

  // phase 1: R1 = relu(rel_pos @ p1 + pb1) for this wave's 16 rows.
  // lane>>2 = local row, lane&3 = part; cp strided by part (2-way banks).
  {
    int lrow = lane >> 2, part = lane & 3;
    int j = Idx[w * 16 + lrow];
    int qi = qbase + w;
    const float* cb = can + (size_t)b * NPT * 3;
    float r0 = cb[j * 3 + 0] - cb[qi * 3 + 0];
    float r1 = cb[j * 3 + 1] - cb[qi * 3 + 1];
    float r2 = cb[j * 3 + 2] - cb[qi * 3 + 2];
    #pragma unroll
    for (int hp = 0; hp < 8; ++hp) {
      int cp = part + 4 * hp;
      u32 pack = 0;
      #pragma unroll
      for (int e = 0; e < 2; ++e) {
        int hh = cp * 2 + e;
        float s = r0 * p1[hh];
        s = fmaf(r1, p1[PH + hh], s);
        s = fmaf(r2, p1[2 * PH + hh], s);
        s += pb1[hh];
        s = fmaxf(s, 0.0f);
        pack |= ((u32)f2bf(s)) << (16 * e);
      }
      *(u32*)(R1 + (w * 16 + lrow) * 72 + cp * 2) = pack;
    }
  }
  // same-wave LDS write->read; lgkmcnt ordering (no barrier needed)

  // phase 2: rpe = R1@p2 + pb2 (16 MFMA, rows=this wave's 16, cols=all 128);
  // combine with prefetched pv: Xt=qk+rpe (LDS), vp=v+rpe (packed registers)
  u32 vp[4][4];
  {
    f32x4 acc[8];
    #pragma unroll
    for (int tn = 0; tn < 8; ++tn) acc[tn] = (f32x4){0.f, 0.f, 0.f, 0.f};
    #pragma unroll
    for (int ks = 0; ks < 2; ++ks) {
      int k0 = ks * 32 + quad * 8;
      short8 afr = *(const short8*)(R1 + (w * 16 + fm) * 72 + k0);
      #pragma unroll
      for (int tn = 0; tn < 8; ++tn) {
        short8 bfr = *(const short8*)(p2T + (tn * 16 + fm) * PH + k0);
        acc[tn] = __builtin_amdgcn_mfma_f32_16x16x32_bf16(afr, bfr, acc[tn], 0, 0, 0);
      }
    }
    #pragma unroll
    for (int tn = 0; tn < 8; ++tn) {
      int col = tn * 16 + fm;
      float pb2c = pb2[col];
      #pragma unroll
      for (int r = 0; r < 4; ++r) {
        int row = w * 16 + quad * 4 + r;
        float rpe = acc[tn][r] + pb2c;
        u32 wv2 = pvld[tn][r];
        Xt[row * XT_LD + col] = f2bf(bf2f((u16)(wv2 & 0xffffu)) + rpe);
        u32 vb = (u32)f2bf(bf2f((u16)(wv2 >> 16)) + rpe);
        if ((tn & 1) == 0) vp[tn >> 1][r] = vb;
        else vp[tn >> 1][r] |= vb << 16;
      }
    }
  }
  // same-wave Xt write->read below; lgkmcnt ordering

  // phase 3: S = relu(X@a1+ab1)@a2, 4 chunks, fully wave-private.
  // H round-trip through wave-private Hs rows (C-layout -> A-layout).
  f32x4 accS[8];
  #pragma unroll
  for (int tn = 0; tn < 8; ++tn) accS[tn] = (f32x4){0.f, 0.f, 0.f, 0.f};
  #pragma unroll 1
  for (int c = 0; c < 4; ++c) {
    f32x4 acc1[8];
    #pragma unroll
    for (int tn = 0; tn < 8; ++tn) acc1[tn] = (f32x4){0.f, 0.f, 0.f, 0.f};
    #pragma unroll
    for (int ks = 0; ks < 4; ++ks) {
      int k0 = ks * 32 + quad * 8;
      short8 afr = *(const short8*)(Xt + (w * 16 + fm) * XT_LD + k0);
      #pragma unroll
      for (int tn = 0; tn < 8; ++tn) {
        short8 bfr = *(const short8*)(a1T + (c * 128 + tn * 16 + fm) * 128 + k0);
        acc1[tn] = __builtin_amdgcn_mfma_f32_16x16x32_bf16(afr, bfr, acc1[tn], 0, 0, 0);
      }
    }
    #pragma unroll
    for (int tn = 0; tn < 8; ++tn) {
      int lcol = tn * 16 + fm;
      float ab1c = ab1[c * 128 + lcol];
      #pragma unroll
      for (int r = 0; r < 4; ++r) {
        int row = w * 16 + quad * 4 + r;
        Hs[row * XT_LD + lcol] = f2bf(fmaxf(acc1[tn][r] + ab1c, 0.0f));
      }
    }
    // same-wave Hs write->read; lgkmcnt ordering
    #pragma unroll
    for (int ks = 0; ks < 4; ++ks) {
      int k0 = ks * 32 + quad * 8;
      short8 afr = *(const short8*)(Hs + (w * 16 + fm) * XT_LD + k0);
      #pragma unroll
      for (int tn = 0; tn < 8; ++tn) {
        short8 bfr = *(const short8*)(a2T + (tn * 16 + fm) * AH + c * 128 + k0);
        accS[tn] = __builtin_amdgcn_mfma_f32_16x16x32_bf16(afr, bfr, accS[tn], 0, 0, 0);
      }
    }
  }

  // phase 4: softmax over 128 features per row — wave-local (fm shuffles).
  {
    float ab2c[8];
    #pragma unroll
    for (int tn = 0; tn < 8; ++tn) ab2c[tn] = ab2[tn * 16 + fm];
    float rm[4], sm[4];
    #pragma unroll
    for (int r = 0; r < 4; ++r) {
      float m = accS[0][r] + ab2c[0];
      #pragma unroll
      for (int tn = 0; tn < 8; ++tn) {
        accS[tn][r] += ab2c[tn];
        m = fmaxf(m, accS[tn][r]);
      }
      rm[r] = m;
    }
    #pragma unroll
    for (int off = 1; off <= 8; off <<= 1)
      #pragma unroll
      for (int r = 0; r < 4; ++r)
        rm[r] = fmaxf(rm[r], __shfl_xor(rm[r], off));
    #pragma unroll
    for (int r = 0; r < 4; ++r) {
      float s = 0.f;
      #pragma unroll
      for (int tn = 0; tn < 8; ++tn) {
        float e = __expf(accS[tn][r] - rm[r]);
        accS[tn][r] = e;
        s += e;
      }
      sm[r] = s;
    }
    #pragma unroll
    for (int off = 1; off <= 8; off <<= 1)
      #pragma unroll
      for (int r = 0; r < 4; ++r)
        sm[r] += __shfl_xor(sm[r], off);
    #pragma unroll
    for (int r = 0; r < 4; ++r) {
      float inv = 1.0f / sm[r];   // sum >= exp(0) = 1
      #pragma unroll
      for (int tn = 0; tn < 8; ++tn) accS[tn][r] *= inv;
    }
  }

  // phase 5: L2-norm over 16 neighbors + aggregate — quad shuffles.
  #pragma unroll
  for (int tn = 0; tn < 8; ++tn) {
    float ssq = 0.f, wav = 0.f;
    #pragma unroll
    for (int r = 0; r < 4; ++r) {
      float a = accS[tn][r];
      u16 vb = (u16)((tn & 1) == 0 ? (vp[tn >> 1][r] & 0xffffu)
                                   : (vp[tn >> 1][r] >> 16));
      ssq = fmaf(a, a, ssq);
      wav = fmaf(a, bf2f(vb), wav);
    }
    ssq += __shfl_xor(ssq, 16); ssq += __shfl_xor(ssq, 32);
    wav += __shfl_xor(wav, 16); wav += __shfl_xor(wav, 32);
    if (quad == 0)
      Agg[w * EMB + tn * 16 + fm] = wav / fmaxf(sqrtf(ssq), 1e-12f);
  }
  __syncthreads();

  // phase 7: out = Agg @ wo + bo
  {
    int d = tid & 127, qp = tid >> 7;
    float boc = bo[d];
    #pragma unroll
    for (int qi2 = 0; qi2 < 2; ++qi2) {
      int q = qp * 2 + qi2;
      float o = 0.f;
      #pragma unroll
      for (int k8 = 0; k8 < 16; ++k8) {
        short8 w8 = *(const short8*)(woT + d * 128 + k8 * 8);
        #pragma unroll
        for (int e = 0; e < 8; ++e)
          o = fmaf(Agg[q * EMB + k8 * 8 + e], bf2f((u16)w8[e]), o);
      }
      out[((size_t)b * NPT + qbase + q) * EMB + d] = o + boc;
    }
  }
}

// ---------------------------------------------------------------- launch
extern "C" void kernel_launch(void* const* d_in, const int* in_sizes, int n_in,
                              void* d_out, int out_size, void* d_ws, size_t ws_size,
                              hipStream_t stream) {
  (void)in_sizes; (void)n_in; (void)out_size; (void)ws_size;
  const float* query = (const float*)d_in[0];
  const float* key_i = (const float*)d_in[1];
  const float* value = (const float*)d_in[2];
  const float* can   = (const float*)d_in[3];
  const float* wq  = (const float*)d_in[4];
  const float* wk  = (const float*)d_in[5];
  const float* wv  = (const float*)d_in[6];
  const float* wo  = (const float*)d_in[7];
  const float* bo  = (const float*)d_in[8];
  const float* p1  = (const float*)d_in[9];
  const float* pb1 = (const float*)d_in[10];
  const float* p2  = (const float*)d_in[11];
  const float* pb2 = (const float*)d_in[12];
  const float* a1  = (const float*)d_in[13];
  const float* ab1 = (const float*)d_in[14];
  const float* a2  = (const float*)d_in[15];
  const float* ab2 = (const float*)d_in[16];

  char* ws = (char*)d_ws;
  u32* pv_ws = (u32*)(ws + 0);            // 4*2048*128 u32 = 4 MiB
  int* idx_ws  = (int*)(ws + 8388608);    // 512 KiB
  u16* wqT = (u16*)(ws + 8912896);
  u16* wkT = (u16*)(ws + 8945664);
  u16* wvT = (u16*)(ws + 8978432);
  u16* p2T = (u16*)(ws + 9011200);
  u16* a1T = (u16*)(ws + 9027584);
  u16* a2T = (u16*)(ws + 9158656);
  u16* woT = (u16*)(ws + 9289728);
  float* out = (float*)d_out;

  k_transpose<<<dim3(7), dim3(256), 0, stream>>>(
      wq, wk, wv, p2, a1, a2, wo, wqT, wkT, wvT, p2T, a1T, a2T, woT);
  k_knn<<<dim3(1024), dim3(256), 0, stream>>>(can, idx_ws);
  k_qkv<<<dim3(128), dim3(256), 0, stream>>>(
      query, key_i, value, wqT, wkT, wvT, pv_ws);
  k_attn<<<dim3(2048), dim3(256), 0, stream>>>(
      can, pv_ws, idx_ws, p1, pb1, p2T, pb2, a1T, ab1, a2T, ab2,
      woT, bo, out);
}

// Round 18
// 344.670 us; speedup vs baseline: 1.4236x; 1.4236x over previous
//
#include <hip/hip_runtime.h>
#include <stdint.h>

typedef unsigned short u16;
typedef unsigned int u32;
typedef unsigned long long u64;
typedef __attribute__((ext_vector_type(8))) short short8;
typedef __attribute__((ext_vector_type(4))) float f32x4;

#define BSZ 4
#define NPT 2048
#define EMB 128
#define PH  64
#define AH  512
#define KNB 16

__device__ __forceinline__ u16 f2bf(float f) {
  union { float f; u32 u; } v; v.f = f;
  u32 r = (v.u >> 16) & 1u;
  v.u += 0x7fffu + r;
  return (u16)(v.u >> 16);
}
__device__ __forceinline__ float bf2f(u16 x) {
  union { u32 u; float f; } v; v.u = ((u32)x) << 16; return v.f;
}

// ---------------------------------------------------------------- transpose
__global__ __launch_bounds__(256) void k_transpose(
    const float* wq, const float* wk, const float* wv, const float* p2,
    const float* a1, const float* a2, const float* wo,
    u16* wqT, u16* wkT, u16* wvT, u16* p2T, u16* a1T, u16* a2T, u16* woT) {
  const float* src; u16* dst; int K, Nn;
  switch (blockIdx.x) {
    case 0: src = wq; dst = wqT; K = 128; Nn = 128; break;
    case 1: src = wk; dst = wkT; K = 128; Nn = 128; break;
    case 2: src = wv; dst = wvT; K = 128; Nn = 128; break;
    case 3: src = p2; dst = p2T; K = 64;  Nn = 128; break;
    case 4: src = a1; dst = a1T; K = 128; Nn = 512; break;
    case 5: src = a2; dst = a2T; K = 512; Nn = 128; break;
    default: src = wo; dst = woT; K = 128; Nn = 128; break;
  }
  for (int n = threadIdx.x; n < Nn; n += 256) {
    for (int k0 = 0; k0 < K; k0 += 8) {
      short8 vv;
      #pragma unroll
      for (int t = 0; t < 8; ++t)
        vv[t] = (short)f2bf(src[(k0 + t) * Nn + n]);
      *(short8*)(dst + n * K + k0) = vv;
    }
  }
}

// ---------------------------------------------------------------- knn
// Passing r13 version, unchanged. CURSE LOG: r4/r5/r9 restructures of the
// extraction loop all produced identical wrong output (absmax 0.71875) —
// only this r2 idiom passes; scheduling/memory-source changes at most.
__device__ __forceinline__ u32 f2sort(float f) {
  union { float f; u32 u; } v; v.f = f;
  return v.u ^ ((v.u >> 31) ? 0xFFFFFFFFu : 0x80000000u);
}

__global__ __launch_bounds__(256) void k_knn(const float* __restrict__ can,
                                             int* __restrict__ idx_out) {
  __shared__ float dists[4][NPT];
  int b = blockIdx.x >> 8;
  int qblk = blockIdx.x & 255;
  const float* cb = can + (size_t)b * NPT * 3;
  int wave = threadIdx.x >> 6, lane = threadIdx.x & 63;
  float* dw = dists[wave];
  #pragma unroll 1
  for (int t = 0; t < 2; ++t) {
    int i = qblk * 8 + wave * 2 + t;
    float xi = cb[i * 3 + 0], yi = cb[i * 3 + 1], zi = cb[i * 3 + 2];
    float sqi = __fadd_rn(__fadd_rn(__fmul_rn(xi, xi), __fmul_rn(yi, yi)),
                          __fmul_rn(zi, zi));
    u64 lmin = ~0ull;
    #pragma unroll 4
    for (int c = 0; c < NPT / 64; ++c) {
      int j = c * 64 + lane;
      const float* pj = cb + j * 3;
      float xj = pj[0], yj = pj[1], zj = pj[2];
      float sqj = __fadd_rn(__fadd_rn(__fmul_rn(xj, xj), __fmul_rn(yj, yj)),
                            __fmul_rn(zj, zj));
      float nn = __fadd_rn(__fadd_rn(__fmul_rn(xi, xj), __fmul_rn(yi, yj)),
                           __fmul_rn(zi, zj));
      float dist = __fadd_rn(__fsub_rn(sqi, __fmul_rn(2.0f, nn)), sqj);
      dw[j] = dist;
      u64 key = (((u64)f2sort(dist)) << 32) | (u32)j;
      lmin = key < lmin ? key : lmin;
    }
    #pragma unroll 1
    for (int r = 0; r < KNB; ++r) {
      u64 g = lmin;
      #pragma unroll
      for (int off = 32; off > 0; off >>= 1) {
        u64 o = __shfl_xor(g, off);
        g = o < g ? o : g;
      }
      int jw = (int)(u32)(g & 0xffffffffull);
      if (lane == 0) idx_out[((size_t)b * NPT + i) * KNB + r] = jw;
      if ((jw & 63) == lane) {
        union { u32 u; float f; } inf; inf.u = 0x7f800000u;
        dw[jw] = inf.f;
        lmin = ~0ull;
        #pragma unroll
        for (int c = 0; c < NPT / 64; ++c) {
          int j = c * 64 + lane;
          u64 key = (((u64)f2sort(dw[j])) << 32) | (u32)j;
          lmin = key < lmin ? key : lmin;
        }
      }
    }
  }
}

// ---------------------------------------------------------------- qkv
// pv[point][col] = bf16(q@wq - k@wk) | bf16(v@wv)<<16 (one gather stream).
__device__ __forceinline__ void qkv_gemm(const u16* At, const u16* wT,
                                         int colbase, int fm, int quad,
                                         f32x4 acc[2][4]) {
  #pragma unroll
  for (int tn = 0; tn < 2; ++tn)
    #pragma unroll
    for (int tm = 0; tm < 4; ++tm) acc[tn][tm] = (f32x4){0.f, 0.f, 0.f, 0.f};
  #pragma unroll
  for (int ks = 0; ks < 4; ++ks) {
    int k0 = ks * 32 + quad * 8;
    short8 bfr0 = *(const short8*)(wT + (colbase + fm) * 128 + k0);
    short8 bfr1 = *(const short8*)(wT + (colbase + 16 + fm) * 128 + k0);
    #pragma unroll
    for (int tm = 0; tm < 4; ++tm) {
      short8 afr = *(const short8*)(At + (tm * 16 + fm) * 136 + k0);
      acc[0][tm] = __builtin_amdgcn_mfma_f32_16x16x32_bf16(afr, bfr0, acc[0][tm], 0, 0, 0);
      acc[1][tm] = __builtin_amdgcn_mfma_f32_16x16x32_bf16(afr, bfr1, acc[1][tm], 0, 0, 0);
    }
  }
}

__device__ __forceinline__ void qkv_stage(u16* At, const float* src, int rbase, int tid) {
  #pragma unroll
  for (int rep = 0; rep < 4; ++rep) {
    int linear = tid + 256 * rep;
    int row = linear >> 4;
    int c16 = linear & 15;
    const float* sp = src + (size_t)(rbase + row) * 128 + c16 * 8;
    f32x4 a = *(const f32x4*)(sp);
    f32x4 b = *(const f32x4*)(sp + 4);
    short8 vv;
    vv[0] = (short)f2bf(a[0]); vv[1] = (short)f2bf(a[1]);
    vv[2] = (short)f2bf(a[2]); vv[3] = (short)f2bf(a[3]);
    vv[4] = (short)f2bf(b[0]); vv[5] = (short)f2bf(b[1]);
    vv[6] = (short)f2bf(b[2]); vv[7] = (short)f2bf(b[3]);
    *(short8*)(At + row * 136 + c16 * 8) = vv;
  }
}

__global__ __launch_bounds__(256) void k_qkv(
    const float* __restrict__ query, const float* __restrict__ key,
    const float* __restrict__ value,
    const u16* __restrict__ wqT, const u16* __restrict__ wkT,
    const u16* __restrict__ wvT,
    u32* __restrict__ pv_out) {
  __shared__ __align__(16) u16 At[64 * 136];
  int tid = threadIdx.x;
  int rbase = blockIdx.x * 64;
  int lane = tid & 63, wave = tid >> 6;
  int fm = lane & 15, quad = lane >> 4;
  int colbase = wave * 32;
  f32x4 accq[2][4], acck[2][4];

  qkv_stage(At, query, rbase, tid);
  __syncthreads();
  qkv_gemm(At, wqT, colbase, fm, quad, accq);
  __syncthreads();
  qkv_stage(At, key, rbase, tid);
  __syncthreads();
  qkv_gemm(At, wkT, colbase, fm, quad, acck);
  u32 qk2[4][4];
  #pragma unroll
  for (int tm = 0; tm < 4; ++tm)
    #pragma unroll
    for (int r = 0; r < 4; ++r)
      qk2[tm][r] = (u32)f2bf(accq[0][tm][r] - acck[0][tm][r]) |
                   (((u32)f2bf(accq[1][tm][r] - acck[1][tm][r])) << 16);
  __syncthreads();
  qkv_stage(At, value, rbase, tid);
  __syncthreads();
  qkv_gemm(At, wvT, colbase, fm, quad, accq);
  #pragma unroll
  for (int tn = 0; tn < 2; ++tn) {
    int col = colbase + tn * 16 + fm;
    #pragma unroll
    for (int tm = 0; tm < 4; ++tm)
      #pragma unroll
      for (int r = 0; r < 4; ++r) {
        int row = tm * 16 + quad * 4 + r;
        u32 qkb = tn == 0 ? (qk2[tm][r] & 0xffffu) : (qk2[tm][r] >> 16);
        u32 pack = qkb | (((u32)f2bf(accq[tn][tm][r])) << 16);
        pv_out[(size_t)(rbase + row) * 128 + col] = pack;
      }
  }
}

// ---------------------------------------------------------------- fused attention
// r18 = r16 structure (column-split waves — keeps B-frag loads amortized;
// r17's wave-parallel variant 4x'd weight loads and regressed 139->335us)
// plus two latency fixes:
//  1. double-buffered Hs: removes the end-of-chunk WAR barrier (10->8).
//     LDS 54.5KB -> exactly 3 blocks/CU; Red1/Red2 overlay dead Xt.
//  2. a2 frags (chunk c) + a1 frags (chunk c+1) explicitly loaded into
//     registers BEFORE the chunk barrier — the barrier's vmcnt drain
//     completes the prefetch instead of a post-barrier L2 stall.
#define XT_LD 136

__global__ __launch_bounds__(256, 3) void k_attn(
    const float* __restrict__ can,
    const u32* __restrict__ pv_g,
    const int* __restrict__ idx_g,
    const float* __restrict__ p1, const float* __restrict__ pb1,
    const u16* __restrict__ p2T, const float* __restrict__ pb2,
    const u16* __restrict__ a1T, const float* __restrict__ ab1,
    const u16* __restrict__ a2T, const float* __restrict__ ab2,
    const u16* __restrict__ woT, const float* __restrict__ bo,
    float* __restrict__ out) {
  __shared__ __align__(16) char smem[54528];
  u16* Xt = (u16*)(smem);                // [64][136] bf16 (dead after phase 3)
  // Hs double buffer: smem+17408 and smem+34816, each [64][136] bf16
  float* Red1 = (float*)(smem);          // overlay Xt (phase 4)
  float* Red2 = (float*)(smem + 1024);   // overlay Xt (phase 4)
  float* Agg = (float*)(smem + 52224);   // [4][128] f32
  int* Idx = (int*)(smem + 54272);       // [64]

  const int b = blockIdx.x >> 9;
  const int qbase = (blockIdx.x & 511) * 4;
  const int tid = threadIdx.x;
  const int lane = tid & 63, wave = tid >> 6;
  const int fm = lane & 15, quad = lane >> 4;
  const int colbase = wave * 32;

  if (tid < 64) Idx[tid] = idx_g[((size_t)b * NPT + qbase) * KNB + tid];
  __syncthreads();

  // prefetch the 32 pv gathers; latency hides under phase 1 + MFMA
  u32 pvld[2][4][4];
  #pragma unroll
  for (int tn = 0; tn < 2; ++tn) {
    int col = colbase + tn * 16 + fm;
    #pragma unroll
    for (int tm = 0; tm < 4; ++tm)
      #pragma unroll
      for (int r = 0; r < 4; ++r) {
        int row = tm * 16 + quad * 4 + r;
        int j = Idx[row];
        pvld[tn][tm][r] = pv_g[((size_t)b * NPT + j) * EMB + col];
      }
  }

  // phase 1: R1 = relu(rel_pos @ p1 + pb1) -> low half of Hs buffer 0 region
  // (R1 overlays Hs[0]; dead before first Hs[0] write in chunk 0)
  u16* R1 = (u16*)(smem + 17408);
  {
    int row = tid >> 2, part = tid & 3;
    int j = Idx[row];
    int qi = qbase + (row >> 4);
    const float* cb = can + (size_t)b * NPT * 3;
    float r0 = cb[j * 3 + 0] - cb[qi * 3 + 0];
    float r1 = cb[j * 3 + 1] - cb[qi * 3 + 1];
    float r2 = cb[j * 3 + 2] - cb[qi * 3 + 2];
    #pragma unroll
    for (int hp = 0; hp < 8; ++hp) {
      int cp = part + 4 * hp;
      u32 pack = 0;
      #pragma unroll
      for (int e = 0; e < 2; ++e) {
        int hh = cp * 2 + e;
        float s = r0 * p1[hh];
        s = fmaf(r1, p1[PH + hh], s);
        s = fmaf(r2, p1[2 * PH + hh], s);
        s += pb1[hh];
        s = fmaxf(s, 0.0f);
        pack |= ((u32)f2bf(s)) << (16 * e);
      }
      *(u32*)(R1 + row * 72 + cp * 2) = pack;
    }
  }
  __syncthreads();

  // phase 2: rpe = R1@p2 + pb2 (MFMA); combine with prefetched pv:
  // Xt = qk+rpe (LDS), vp = v+rpe (packed bf16 registers)
  u32 vp[4][4];
  {
    f32x4 acc[2][4];
    #pragma unroll
    for (int tn = 0; tn < 2; ++tn)
      #pragma unroll
      for (int tm = 0; tm < 4; ++tm) acc[tn][tm] = (f32x4){0.f, 0.f, 0.f, 0.f};
    #pragma unroll
    for (int ks = 0; ks < 2; ++ks) {
      int k0 = ks * 32 + quad * 8;
      short8 bfr0 = *(const short8*)(p2T + (colbase + fm) * PH + k0);
      short8 bfr1 = *(const short8*)(p2T + (colbase + 16 + fm) * PH + k0);
      #pragma unroll
      for (int tm = 0; tm < 4; ++tm) {
        short8 afr = *(const short8*)(R1 + (tm * 16 + fm) * 72 + k0);
        acc[0][tm] = __builtin_amdgcn_mfma_f32_16x16x32_bf16(afr, bfr0, acc[0][tm], 0, 0, 0);
        acc[1][tm] = __builtin_amdgcn_mfma_f32_16x16x32_bf16(afr, bfr1, acc[1][tm], 0, 0, 0);
      }
    }
    #pragma unroll
    for (int tn = 0; tn < 2; ++tn) {
      int col = colbase + tn * 16 + fm;
      float pb2c = pb2[col];
      #pragma unroll
      for (int tm = 0; tm < 4; ++tm)
        #pragma unroll
        for (int r = 0; r < 4; ++r) {
          int row = tm * 16 + quad * 4 + r;
          float rpe = acc[tn][tm][r] + pb2c;
          u32 w = pvld[tn][tm][r];
          Xt[row * XT_LD + col] = f2bf(bf2f((u16)(w & 0xffffu)) + rpe);
          u32 vb = (u32)f2bf(bf2f((u16)(w >> 16)) + rpe);
          if (tn == 0) vp[tm][r] = vb; else vp[tm][r] |= vb << 16;
        }
    }
  }
  __syncthreads();   // Xt ready; also R1 (Hs[0] overlay) dead after this

  // phase 3: S = relu(X@a1+ab1)@a2, 4 chunks; double-buffered Hs,
  // B-frags prefetched across the single per-chunk barrier.
  short8 a1f[4][2], a2f[4][2];
  #pragma unroll
  for (int ks = 0; ks < 4; ++ks) {
    int k0 = ks * 32 + quad * 8;
    a1f[ks][0] = *(const short8*)(a1T + (colbase + fm) * 128 + k0);
    a1f[ks][1] = *(const short8*)(a1T + (colbase + 16 + fm) * 128 + k0);
  }
  f32x4 accS[2][4];
  #pragma unroll
  for (int tn = 0; tn < 2; ++tn)
    #pragma unroll
    for (int tm = 0; tm < 4; ++tm) accS[tn][tm] = (f32x4){0.f, 0.f, 0.f, 0.f};
  #pragma unroll 1
  for (int c = 0; c < 4; ++c) {
    u16* HsB = (u16*)(smem + 17408 + (c & 1) * 17408);
    f32x4 acc1[2][4];
    #pragma unroll
    for (int tn = 0; tn < 2; ++tn)
      #pragma unroll
      for (int tm = 0; tm < 4; ++tm) acc1[tn][tm] = (f32x4){0.f, 0.f, 0.f, 0.f};
    #pragma unroll
    for (int ks = 0; ks < 4; ++ks) {
      int k0 = ks * 32 + quad * 8;
      #pragma unroll
      for (int tm = 0; tm < 4; ++tm) {
        short8 afr = *(const short8*)(Xt + (tm * 16 + fm) * XT_LD + k0);
        acc1[0][tm] = __builtin_amdgcn_mfma_f32_16x16x32_bf16(afr, a1f[ks][0], acc1[0][tm], 0, 0, 0);
        acc1[1][tm] = __builtin_amdgcn_mfma_f32_16x16x32_bf16(afr, a1f[ks][1], acc1[1][tm], 0, 0, 0);
      }
    }
    #pragma unroll
    for (int tn = 0; tn < 2; ++tn) {
      int lcol = colbase + tn * 16 + fm;
      float ab1c = ab1[c * 128 + lcol];
      #pragma unroll
      for (int tm = 0; tm < 4; ++tm)
        #pragma unroll
        for (int r = 0; r < 4; ++r) {
          int row = tm * 16 + quad * 4 + r;
          HsB[row * XT_LD + lcol] = f2bf(fmaxf(acc1[tn][tm][r] + ab1c, 0.0f));
        }
    }
    // prefetch a2 frags (chunk c) + a1 frags (chunk c+1) BEFORE the barrier
    #pragma unroll
    for (int ks = 0; ks < 4; ++ks) {
      int k0 = ks * 32 + quad * 8;
      a2f[ks][0] = *(const short8*)(a2T + (colbase + fm) * AH + c * 128 + k0);
      a2f[ks][1] = *(const short8*)(a2T + (colbase + 16 + fm) * AH + c * 128 + k0);
    }
    if (c < 3) {
      #pragma unroll
      for (int ks = 0; ks < 4; ++ks) {
        int k0 = ks * 32 + quad * 8;
        a1f[ks][0] = *(const short8*)(a1T + ((c + 1) * 128 + colbase + fm) * 128 + k0);
        a1f[ks][1] = *(const short8*)(a1T + ((c + 1) * 128 + colbase + 16 + fm) * 128 + k0);
      }
    }
    __syncthreads();   // Hs chunk visible to all waves; prefetches complete
    #pragma unroll
    for (int ks = 0; ks < 4; ++ks) {
      int k0 = ks * 32 + quad * 8;
      #pragma unroll
      for (int tm = 0; tm < 4; ++tm) {
        short8 afr = *(const short8*)(HsB + (tm * 16 + fm) * XT_LD + k0);
        accS[0][tm] = __builtin_amdgcn_mfma_f32_16x16x32_bf16(afr, a2f[ks][0], accS[0][tm], 0, 0, 0);
        accS[1][tm] = __builtin_amdgcn_mfma_f32_16x16x32_bf16(afr, a2f[ks][1], accS[1][tm], 0, 0, 0);
      }
    }
    // no trailing barrier: next chunk writes the OTHER Hs buffer; reuse of
    // this buffer (chunk c+2) is fenced by chunk c+1's barrier.
  }

  // phase 4: softmax over 128 features per row (Red1/Red2 overlay dead Xt;
  // all Xt reads are fenced by chunk 3's barrier).
  {
    float ab2c0 = ab2[colbase + fm];
    float ab2c1 = ab2[colbase + 16 + fm];
    float rm[4][4];
    #pragma unroll
    for (int tm = 0; tm < 4; ++tm)
      #pragma unroll
      for (int r = 0; r < 4; ++r) {
        accS[0][tm][r] += ab2c0;
        accS[1][tm][r] += ab2c1;
        rm[tm][r] = fmaxf(accS[0][tm][r], accS[1][tm][r]);
      }
    #pragma unroll
    for (int off = 1; off <= 8; off <<= 1)
      #pragma unroll
      for (int tm = 0; tm < 4; ++tm)
        #pragma unroll
        for (int r = 0; r < 4; ++r)
          rm[tm][r] = fmaxf(rm[tm][r], __shfl_xor(rm[tm][r], off));
    if (fm == 0) {
      #pragma unroll
      for (int tm = 0; tm < 4; ++tm)
        #pragma unroll
        for (int r = 0; r < 4; ++r)
          Red1[wave * 64 + tm * 16 + quad * 4 + r] = rm[tm][r];
    }
    __syncthreads();
    #pragma unroll
    for (int tm = 0; tm < 4; ++tm)
      #pragma unroll
      for (int r = 0; r < 4; ++r) {
        int row = tm * 16 + quad * 4 + r;
        float m = fmaxf(fmaxf(Red1[row], Red1[64 + row]),
                        fmaxf(Red1[128 + row], Red1[192 + row]));
        float e0 = __expf(accS[0][tm][r] - m);
        float e1 = __expf(accS[1][tm][r] - m);
        accS[0][tm][r] = e0;
        accS[1][tm][r] = e1;
        rm[tm][r] = e0 + e1;
      }
    #pragma unroll
    for (int off = 1; off <= 8; off <<= 1)
      #pragma unroll
      for (int tm = 0; tm < 4; ++tm)
        #pragma unroll
        for (int r = 0; r < 4; ++r)
          rm[tm][r] += __shfl_xor(rm[tm][r], off);
    if (fm == 0) {
      #pragma unroll
      for (int tm = 0; tm < 4; ++tm)
        #pragma unroll
        for (int r = 0; r < 4; ++r)
          Red2[wave * 64 + tm * 16 + quad * 4 + r] = rm[tm][r];
    }
    __syncthreads();
    #pragma unroll
    for (int tm = 0; tm < 4; ++tm)
      #pragma unroll
      for (int r = 0; r < 4; ++r) {
        int row = tm * 16 + quad * 4 + r;
        float sum = (Red2[row] + Red2[64 + row]) +
                    (Red2[128 + row] + Red2[192 + row]);
        float inv = 1.0f / sum;   // sum >= exp(0) = 1
        accS[0][tm][r] *= inv;
        accS[1][tm][r] *= inv;
      }
  }

  // phase 5: L2-norm over the 16 neighbors + aggregate, register-resident.
  #pragma unroll
  for (int tn = 0; tn < 2; ++tn)
    #pragma unroll
    for (int tm = 0; tm < 4; ++tm) {
      float ssq = 0.f, wav = 0.f;
      #pragma unroll
      for (int r = 0; r < 4; ++r) {
        float a = accS[tn][tm][r];
        u16 vb = (u16)(tn == 0 ? (vp[tm][r] & 0xffffu) : (vp[tm][r] >> 16));
        ssq = fmaf(a, a, ssq);
        wav = fmaf(a, bf2f(vb), wav);
      }
      ssq += __shfl_xor(ssq, 16); ssq += __shfl_xor(ssq, 32);
      wav += __shfl_xor(wav, 16); wav += __shfl_xor(wav, 32);
      if (quad == 0)
        Agg[tm * EMB + colbase + tn * 16 + fm] =
            wav / fmaxf(sqrtf(ssq), 1e-12f);
    }
  __syncthreads();

  // phase 7: out = Agg @ wo + bo
  {
    int d = tid & 127, qp = tid >> 7;
    float boc = bo[d];
    #pragma unroll
    for (int qi2 = 0; qi2 < 2; ++qi2) {
      int q = qp * 2 + qi2;
      float o = 0.f;
      #pragma unroll
      for (int k8 = 0; k8 < 16; ++k8) {
        short8 w8 = *(const short8*)(woT + d * 128 + k8 * 8);
        #pragma unroll
        for (int e = 0; e < 8; ++e)
          o = fmaf(Agg[q * EMB + k8 * 8 + e], bf2f((u16)w8[e]), o);
      }
      out[((size_t)b * NPT + qbase + q) * EMB + d] = o + boc;
    }
  }
}

// ---------------------------------------------------------------- launch
extern "C" void kernel_launch(void* const* d_in, const int* in_sizes, int n_in,
                              void* d_out, int out_size, void* d_ws, size_t ws_size,
                              hipStream_t stream) {
  (void)in_sizes; (void)n_in; (void)out_size; (void)ws_size;
  const float* query = (const float*)d_in[0];
  const float* key_i = (const float*)d_in[1];
  const float* value = (const float*)d_in[2];
  const float* can   = (const float*)d_in[3];
  const float* wq  = (const float*)d_in[4];
  const float* wk  = (const float*)d_in[5];
  const float* wv  = (const float*)d_in[6];
  const float* wo  = (const float*)d_in[7];
  const float* bo  = (const float*)d_in[8];
  const float* p1  = (const float*)d_in[9];
  const float* pb1 = (const float*)d_in[10];
  const float* p2  = (const float*)d_in[11];
  const float* pb2 = (const float*)d_in[12];
  const float* a1  = (const float*)d_in[13];
  const float* ab1 = (const float*)d_in[14];
  const float* a2  = (const float*)d_in[15];
  const float* ab2 = (const float*)d_in[16];

  char* ws = (char*)d_ws;
  u32* pv_ws = (u32*)(ws + 0);            // 4*2048*128 u32 = 4 MiB
  int* idx_ws  = (int*)(ws + 8388608);    // 512 KiB
  u16* wqT = (u16*)(ws + 8912896);
  u16* wkT = (u16*)(ws + 8945664);
  u16* wvT = (u16*)(ws + 8978432);
  u16* p2T = (u16*)(ws + 9011200);
  u16* a1T = (u16*)(ws + 9027584);
  u16* a2T = (u16*)(ws + 9158656);
  u16* woT = (u16*)(ws + 9289728);
  float* out = (float*)d_out;

  k_transpose<<<dim3(7), dim3(256), 0, stream>>>(
      wq, wk, wv, p2, a1, a2, wo, wqT, wkT, wvT, p2T, a1T, a2T, woT);
  k_knn<<<dim3(1024), dim3(256), 0, stream>>>(can, idx_ws);
  k_qkv<<<dim3(128), dim3(256), 0, stream>>>(
      query, key_i, value, wqT, wkT, wvT, pv_ws);
  k_attn<<<dim3(2048), dim3(256), 0, stream>>>(
      can, pv_ws, idx_ws, p1, pb1, p2T, pb2, a1T, ab1, a2T, ab2,
      woT, bo, out);
}

// Round 19
// 318.288 us; speedup vs baseline: 1.5416x; 1.0829x over previous
//
#include <hip/hip_runtime.h>
#include <stdint.h>

typedef unsigned short u16;
typedef unsigned int u32;
typedef unsigned long long u64;
typedef __attribute__((ext_vector_type(8))) short short8;
typedef __attribute__((ext_vector_type(4))) float f32x4;

#define BSZ 4
#define NPT 2048
#define EMB 128
#define PH  64
#define AH  512
#define KNB 16

__device__ __forceinline__ u16 f2bf(float f) {
  union { float f; u32 u; } v; v.f = f;
  u32 r = (v.u >> 16) & 1u;
  v.u += 0x7fffu + r;
  return (u16)(v.u >> 16);
}
__device__ __forceinline__ float bf2f(u16 x) {
  union { u32 u; float f; } v; v.u = ((u32)x) << 16; return v.f;
}

// ---------------------------------------------------------------- transpose
__global__ __launch_bounds__(256) void k_transpose(
    const float* wq, const float* wk, const float* wv, const float* p2,
    const float* a1, const float* a2, const float* wo,
    u16* wqT, u16* wkT, u16* wvT, u16* p2T, u16* a1T, u16* a2T, u16* woT) {
  const float* src; u16* dst; int K, Nn;
  switch (blockIdx.x) {
    case 0: src = wq; dst = wqT; K = 128; Nn = 128; break;
    case 1: src = wk; dst = wkT; K = 128; Nn = 128; break;
    case 2: src = wv; dst = wvT; K = 128; Nn = 128; break;
    case 3: src = p2; dst = p2T; K = 64;  Nn = 128; break;
    case 4: src = a1; dst = a1T; K = 128; Nn = 512; break;
    case 5: src = a2; dst = a2T; K = 512; Nn = 128; break;
    default: src = wo; dst = woT; K = 128; Nn = 128; break;
  }
  for (int n = threadIdx.x; n < Nn; n += 256) {
    for (int k0 = 0; k0 < K; k0 += 8) {
      short8 vv;
      #pragma unroll
      for (int t = 0; t < 8; ++t)
        vv[t] = (short)f2bf(src[(k0 + t) * Nn + n]);
      *(short8*)(dst + n * K + k0) = vv;
    }
  }
}

// ---------------------------------------------------------------- knn
// Passing r13 version, unchanged. CURSE LOG: r4/r5/r9 restructures of the
// extraction loop all produced identical wrong output (absmax 0.71875) —
// only this r2 idiom passes; scheduling/memory-source changes at most.
__device__ __forceinline__ u32 f2sort(float f) {
  union { float f; u32 u; } v; v.f = f;
  return v.u ^ ((v.u >> 31) ? 0xFFFFFFFFu : 0x80000000u);
}

__global__ __launch_bounds__(256) void k_knn(const float* __restrict__ can,
                                             int* __restrict__ idx_out) {
  __shared__ float dists[4][NPT];
  int b = blockIdx.x >> 8;
  int qblk = blockIdx.x & 255;
  const float* cb = can + (size_t)b * NPT * 3;
  int wave = threadIdx.x >> 6, lane = threadIdx.x & 63;
  float* dw = dists[wave];
  #pragma unroll 1
  for (int t = 0; t < 2; ++t) {
    int i = qblk * 8 + wave * 2 + t;
    float xi = cb[i * 3 + 0], yi = cb[i * 3 + 1], zi = cb[i * 3 + 2];
    float sqi = __fadd_rn(__fadd_rn(__fmul_rn(xi, xi), __fmul_rn(yi, yi)),
                          __fmul_rn(zi, zi));
    u64 lmin = ~0ull;
    #pragma unroll 4
    for (int c = 0; c < NPT / 64; ++c) {
      int j = c * 64 + lane;
      const float* pj = cb + j * 3;
      float xj = pj[0], yj = pj[1], zj = pj[2];
      float sqj = __fadd_rn(__fadd_rn(__fmul_rn(xj, xj), __fmul_rn(yj, yj)),
                            __fmul_rn(zj, zj));
      float nn = __fadd_rn(__fadd_rn(__fmul_rn(xi, xj), __fmul_rn(yi, yj)),
                           __fmul_rn(zi, zj));
      float dist = __fadd_rn(__fsub_rn(sqi, __fmul_rn(2.0f, nn)), sqj);
      dw[j] = dist;
      u64 key = (((u64)f2sort(dist)) << 32) | (u32)j;
      lmin = key < lmin ? key : lmin;
    }
    #pragma unroll 1
    for (int r = 0; r < KNB; ++r) {
      u64 g = lmin;
      #pragma unroll
      for (int off = 32; off > 0; off >>= 1) {
        u64 o = __shfl_xor(g, off);
        g = o < g ? o : g;
      }
      int jw = (int)(u32)(g & 0xffffffffull);
      if (lane == 0) idx_out[((size_t)b * NPT + i) * KNB + r] = jw;
      if ((jw & 63) == lane) {
        union { u32 u; float f; } inf; inf.u = 0x7f800000u;
        dw[jw] = inf.f;
        lmin = ~0ull;
        #pragma unroll
        for (int c = 0; c < NPT / 64; ++c) {
          int j = c * 64 + lane;
          u64 key = (((u64)f2sort(dw[j])) << 32) | (u32)j;
          lmin = key < lmin ? key : lmin;
        }
      }
    }
  }
}

// ---------------------------------------------------------------- qkv
// r19: 256 blocks x 32 rows (was 128 x 64 — HALF THE GPU IDLE by grid).
// Per-row math identical -> identical pv bits.
// pv[point][col] = bf16(q@wq - k@wk) | bf16(v@wv)<<16 (one gather stream).
__device__ __forceinline__ void qkv_gemm32(const u16* At, const u16* wT,
                                           int colbase, int fm, int quad,
                                           f32x4 acc[2][2]) {
  #pragma unroll
  for (int tn = 0; tn < 2; ++tn)
    #pragma unroll
    for (int tm = 0; tm < 2; ++tm) acc[tn][tm] = (f32x4){0.f, 0.f, 0.f, 0.f};
  #pragma unroll
  for (int ks = 0; ks < 4; ++ks) {
    int k0 = ks * 32 + quad * 8;
    short8 bfr0 = *(const short8*)(wT + (colbase + fm) * 128 + k0);
    short8 bfr1 = *(const short8*)(wT + (colbase + 16 + fm) * 128 + k0);
    #pragma unroll
    for (int tm = 0; tm < 2; ++tm) {
      short8 afr = *(const short8*)(At + (tm * 16 + fm) * 136 + k0);
      acc[0][tm] = __builtin_amdgcn_mfma_f32_16x16x32_bf16(afr, bfr0, acc[0][tm], 0, 0, 0);
      acc[1][tm] = __builtin_amdgcn_mfma_f32_16x16x32_bf16(afr, bfr1, acc[1][tm], 0, 0, 0);
    }
  }
}

__device__ __forceinline__ void qkv_stage32(u16* At, const float* src, int rbase, int tid) {
  #pragma unroll
  for (int rep = 0; rep < 2; ++rep) {
    int linear = tid + 256 * rep;
    int row = linear >> 4;
    int c16 = linear & 15;
    const float* sp = src + (size_t)(rbase + row) * 128 + c16 * 8;
    f32x4 a = *(const f32x4*)(sp);
    f32x4 b = *(const f32x4*)(sp + 4);
    short8 vv;
    vv[0] = (short)f2bf(a[0]); vv[1] = (short)f2bf(a[1]);
    vv[2] = (short)f2bf(a[2]); vv[3] = (short)f2bf(a[3]);
    vv[4] = (short)f2bf(b[0]); vv[5] = (short)f2bf(b[1]);
    vv[6] = (short)f2bf(b[2]); vv[7] = (short)f2bf(b[3]);
    *(short8*)(At + row * 136 + c16 * 8) = vv;
  }
}

__global__ __launch_bounds__(256) void k_qkv(
    const float* __restrict__ query, const float* __restrict__ key,
    const float* __restrict__ value,
    const u16* __restrict__ wqT, const u16* __restrict__ wkT,
    const u16* __restrict__ wvT,
    u32* __restrict__ pv_out) {
  __shared__ __align__(16) u16 At[32 * 136];
  int tid = threadIdx.x;
  int rbase = blockIdx.x * 32;
  int lane = tid & 63, wave = tid >> 6;
  int fm = lane & 15, quad = lane >> 4;
  int colbase = wave * 32;
  f32x4 accq[2][2], acck[2][2];

  qkv_stage32(At, query, rbase, tid);
  __syncthreads();
  qkv_gemm32(At, wqT, colbase, fm, quad, accq);
  __syncthreads();
  qkv_stage32(At, key, rbase, tid);
  __syncthreads();
  qkv_gemm32(At, wkT, colbase, fm, quad, acck);
  u32 qk2[2][4];
  #pragma unroll
  for (int tm = 0; tm < 2; ++tm)
    #pragma unroll
    for (int r = 0; r < 4; ++r)
      qk2[tm][r] = (u32)f2bf(accq[0][tm][r] - acck[0][tm][r]) |
                   (((u32)f2bf(accq[1][tm][r] - acck[1][tm][r])) << 16);
  __syncthreads();
  qkv_stage32(At, value, rbase, tid);
  __syncthreads();
  qkv_gemm32(At, wvT, colbase, fm, quad, accq);
  #pragma unroll
  for (int tn = 0; tn < 2; ++tn) {
    int col = colbase + tn * 16 + fm;
    #pragma unroll
    for (int tm = 0; tm < 2; ++tm)
      #pragma unroll
      for (int r = 0; r < 4; ++r) {
        int row = tm * 16 + quad * 4 + r;
        u32 qkb = tn == 0 ? (qk2[tm][r] & 0xffffu) : (qk2[tm][r] >> 16);
        u32 pack = qkb | (((u32)f2bf(accq[tn][tm][r])) << 16);
        pv_out[(size_t)(rbase + row) * 128 + col] = pack;
      }
  }
}

// ---------------------------------------------------------------- fused attention
// r19 = EXACT r16 k_attn (best measured: 139us). r17 (wave-parallel) 4x'd
// weight loads -> 335us; r18 (Hs dbuf + a-frag prefetch) overflowed the
// 3-block LDS line AND spilled -> 164us. This structure at (256,3) with
// 39KB LDS is the local optimum; do not add register hoards or LDS.
#define XT_LD 136

__global__ __launch_bounds__(256, 3) void k_attn(
    const float* __restrict__ can,
    const u32* __restrict__ pv_g,
    const int* __restrict__ idx_g,
    const float* __restrict__ p1, const float* __restrict__ pb1,
    const u16* __restrict__ p2T, const float* __restrict__ pb2,
    const u16* __restrict__ a1T, const float* __restrict__ ab1,
    const u16* __restrict__ a2T, const float* __restrict__ ab2,
    const u16* __restrict__ woT, const float* __restrict__ bo,
    float* __restrict__ out) {
  __shared__ __align__(16) char smem[39168];
  u16* Xt = (u16*)(smem);              // [64][136] bf16
  u16* Hs = (u16*)(smem + 17408);      // [64][136] bf16
  u16* R1 = (u16*)(smem + 17408);      // [64][72] bf16 (dead before Hs)
  float* Red1 = (float*)(smem + 34816); // [4][64] f32 row-max partials
  float* Red2 = (float*)(smem + 35840); // [4][64] f32 row-sum partials
  float* Agg = (float*)(smem + 36864); // [4][128] f32
  int* Idx = (int*)(smem + 38912);     // [64]

  const int b = blockIdx.x >> 9;
  const int qbase = (blockIdx.x & 511) * 4;
  const int tid = threadIdx.x;
  const int lane = tid & 63, wave = tid >> 6;
  const int fm = lane & 15, quad = lane >> 4;
  const int colbase = wave * 32;

  if (tid < 64) Idx[tid] = idx_g[((size_t)b * NPT + qbase) * KNB + tid];
  __syncthreads();

  // prefetch the 32 pv gathers NOW; latency hides under phase 1 + MFMA
  u32 pvld[2][4][4];
  #pragma unroll
  for (int tn = 0; tn < 2; ++tn) {
    int col = colbase + tn * 16 + fm;
    #pragma unroll
    for (int tm = 0; tm < 4; ++tm)
      #pragma unroll
      for (int r = 0; r < 4; ++r) {
        int row = tm * 16 + quad * 4 + r;
        int j = Idx[row];
        pvld[tn][tm][r] = pv_g[((size_t)b * NPT + j) * EMB + col];
      }
  }

  // phase 1: R1 = relu(rel_pos @ p1 + pb1), bf16 (4 threads per row).
  {
    int row = tid >> 2, part = tid & 3;
    int j = Idx[row];
    int qi = qbase + (row >> 4);
    const float* cb = can + (size_t)b * NPT * 3;
    float r0 = cb[j * 3 + 0] - cb[qi * 3 + 0];
    float r1 = cb[j * 3 + 1] - cb[qi * 3 + 1];
    float r2 = cb[j * 3 + 2] - cb[qi * 3 + 2];
    #pragma unroll
    for (int hp = 0; hp < 8; ++hp) {
      int cp = part + 4 * hp;
      u32 pack = 0;
      #pragma unroll
      for (int e = 0; e < 2; ++e) {
        int hh = cp * 2 + e;
        float s = r0 * p1[hh];
        s = fmaf(r1, p1[PH + hh], s);
        s = fmaf(r2, p1[2 * PH + hh], s);
        s += pb1[hh];
        s = fmaxf(s, 0.0f);
        pack |= ((u32)f2bf(s)) << (16 * e);
      }
      *(u32*)(R1 + row * 72 + cp * 2) = pack;
    }
  }
  __syncthreads();

  // phase 2: rpe = R1@p2 + pb2 (MFMA); combine with prefetched pv:
  // Xt = qk+rpe (LDS), vp = v+rpe (packed bf16 registers)
  u32 vp[4][4];
  {
    f32x4 acc[2][4];
    #pragma unroll
    for (int tn = 0; tn < 2; ++tn)
      #pragma unroll
      for (int tm = 0; tm < 4; ++tm) acc[tn][tm] = (f32x4){0.f, 0.f, 0.f, 0.f};
    #pragma unroll
    for (int ks = 0; ks < 2; ++ks) {
      int k0 = ks * 32 + quad * 8;
      short8 bfr0 = *(const short8*)(p2T + (colbase + fm) * PH + k0);
      short8 bfr1 = *(const short8*)(p2T + (colbase + 16 + fm) * PH + k0);
      #pragma unroll
      for (int tm = 0; tm < 4; ++tm) {
        short8 afr = *(const short8*)(R1 + (tm * 16 + fm) * 72 + k0);
        acc[0][tm] = __builtin_amdgcn_mfma_f32_16x16x32_bf16(afr, bfr0, acc[0][tm], 0, 0, 0);
        acc[1][tm] = __builtin_amdgcn_mfma_f32_16x16x32_bf16(afr, bfr1, acc[1][tm], 0, 0, 0);
      }
    }
    #pragma unroll
    for (int tn = 0; tn < 2; ++tn) {
      int col = colbase + tn * 16 + fm;
      float pb2c = pb2[col];
      #pragma unroll
      for (int tm = 0; tm < 4; ++tm)
        #pragma unroll
        for (int r = 0; r < 4; ++r) {
          int row = tm * 16 + quad * 4 + r;
          float rpe = acc[tn][tm][r] + pb2c;
          u32 w = pvld[tn][tm][r];
          Xt[row * XT_LD + col] = f2bf(bf2f((u16)(w & 0xffffu)) + rpe);
          u32 vb = (u32)f2bf(bf2f((u16)(w >> 16)) + rpe);
          if (tn == 0) vp[tm][r] = vb; else vp[tm][r] |= vb << 16;
        }
    }
  }
  __syncthreads();

  // phase 3: S = relu(X@a1+ab1)@a2, 4 chunks of 128 hidden cols
  f32x4 accS[2][4];
  #pragma unroll
  for (int tn = 0; tn < 2; ++tn)
    #pragma unroll
    for (int tm = 0; tm < 4; ++tm) accS[tn][tm] = (f32x4){0.f, 0.f, 0.f, 0.f};
  #pragma unroll 1
  for (int c = 0; c < 4; ++c) {
    f32x4 acc1[2][4];
    #pragma unroll
    for (int tn = 0; tn < 2; ++tn)
      #pragma unroll
      for (int tm = 0; tm < 4; ++tm) acc1[tn][tm] = (f32x4){0.f, 0.f, 0.f, 0.f};
    #pragma unroll
    for (int ks = 0; ks < 4; ++ks) {
      int k0 = ks * 32 + quad * 8;
      short8 bfr0 = *(const short8*)(a1T + (c * 128 + colbase + fm) * 128 + k0);
      short8 bfr1 = *(const short8*)(a1T + (c * 128 + colbase + 16 + fm) * 128 + k0);
      #pragma unroll
      for (int tm = 0; tm < 4; ++tm) {
        short8 afr = *(const short8*)(Xt + (tm * 16 + fm) * XT_LD + k0);
        acc1[0][tm] = __builtin_amdgcn_mfma_f32_16x16x32_bf16(afr, bfr0, acc1[0][tm], 0, 0, 0);
        acc1[1][tm] = __builtin_amdgcn_mfma_f32_16x16x32_bf16(afr, bfr1, acc1[1][tm], 0, 0, 0);
      }
    }
    #pragma unroll
    for (int tn = 0; tn < 2; ++tn) {
      int lcol = colbase + tn * 16 + fm;
      float ab1c = ab1[c * 128 + lcol];
      #pragma unroll
      for (int tm = 0; tm < 4; ++tm)
        #pragma unroll
        for (int r = 0; r < 4; ++r) {
          int row = tm * 16 + quad * 4 + r;
          Hs[row * XT_LD + lcol] = f2bf(fmaxf(acc1[tn][tm][r] + ab1c, 0.0f));
        }
    }
    __syncthreads();
    #pragma unroll
    for (int ks = 0; ks < 4; ++ks) {
      int k0 = ks * 32 + quad * 8;
      short8 bfr0 = *(const short8*)(a2T + (colbase + fm) * AH + c * 128 + k0);
      short8 bfr1 = *(const short8*)(a2T + (colbase + 16 + fm) * AH + c * 128 + k0);
      #pragma unroll
      for (int tm = 0; tm < 4; ++tm) {
        short8 afr = *(const short8*)(Hs + (tm * 16 + fm) * XT_LD + k0);
        accS[0][tm] = __builtin_amdgcn_mfma_f32_16x16x32_bf16(afr, bfr0, accS[0][tm], 0, 0, 0);
        accS[1][tm] = __builtin_amdgcn_mfma_f32_16x16x32_bf16(afr, bfr1, accS[1][tm], 0, 0, 0);
      }
    }
    __syncthreads();
  }

  // phase 4: softmax over 128 features per row, register-resident.
  {
    float ab2c0 = ab2[colbase + fm];
    float ab2c1 = ab2[colbase + 16 + fm];
    float rm[4][4];
    #pragma unroll
    for (int tm = 0; tm < 4; ++tm)
      #pragma unroll
      for (int r = 0; r < 4; ++r) {
        accS[0][tm][r] += ab2c0;
        accS[1][tm][r] += ab2c1;
        rm[tm][r] = fmaxf(accS[0][tm][r], accS[1][tm][r]);
      }
    #pragma unroll
    for (int off = 1; off <= 8; off <<= 1)
      #pragma unroll
      for (int tm = 0; tm < 4; ++tm)
        #pragma unroll
        for (int r = 0; r < 4; ++r)
          rm[tm][r] = fmaxf(rm[tm][r], __shfl_xor(rm[tm][r], off));
    if (fm == 0) {
      #pragma unroll
      for (int tm = 0; tm < 4; ++tm)
        #pragma unroll
        for (int r = 0; r < 4; ++r)
          Red1[wave * 64 + tm * 16 + quad * 4 + r] = rm[tm][r];
    }
    __syncthreads();
    #pragma unroll
    for (int tm = 0; tm < 4; ++tm)
      #pragma unroll
      for (int r = 0; r < 4; ++r) {
        int row = tm * 16 + quad * 4 + r;
        float m = fmaxf(fmaxf(Red1[row], Red1[64 + row]),
                        fmaxf(Red1[128 + row], Red1[192 + row]));
        float e0 = __expf(accS[0][tm][r] - m);
        float e1 = __expf(accS[1][tm][r] - m);
        accS[0][tm][r] = e0;
        accS[1][tm][r] = e1;
        rm[tm][r] = e0 + e1;
      }
    #pragma unroll
    for (int off = 1; off <= 8; off <<= 1)
      #pragma unroll
      for (int tm = 0; tm < 4; ++tm)
        #pragma unroll
        for (int r = 0; r < 4; ++r)
          rm[tm][r] += __shfl_xor(rm[tm][r], off);
    if (fm == 0) {
      #pragma unroll
      for (int tm = 0; tm < 4; ++tm)
        #pragma unroll
        for (int r = 0; r < 4; ++r)
          Red2[wave * 64 + tm * 16 + quad * 4 + r] = rm[tm][r];
    }
    __syncthreads();
    #pragma unroll
    for (int tm = 0; tm < 4; ++tm)
      #pragma unroll
      for (int r = 0; r < 4; ++r) {
        int row = tm * 16 + quad * 4 + r;
        float sum = (Red2[row] + Red2[64 + row]) +
                    (Red2[128 + row] + Red2[192 + row]);
        float inv = 1.0f / sum;   // sum >= exp(0) = 1
        accS[0][tm][r] *= inv;
        accS[1][tm][r] *= inv;
      }
  }

  // phase 5: L2-norm over the 16 neighbors + aggregate, register-resident.
  #pragma unroll
  for (int tn = 0; tn < 2; ++tn)
    #pragma unroll
    for (int tm = 0; tm < 4; ++tm) {
      float ssq = 0.f, wav = 0.f;
      #pragma unroll
      for (int r = 0; r < 4; ++r) {
        float a = accS[tn][tm][r];
        u16 vb = (u16)(tn == 0 ? (vp[tm][r] & 0xffffu) : (vp[tm][r] >> 16));
        ssq = fmaf(a, a, ssq);
        wav = fmaf(a, bf2f(vb), wav);
      }
      ssq += __shfl_xor(ssq, 16); ssq += __shfl_xor(ssq, 32);
      wav += __shfl_xor(wav, 16); wav += __shfl_xor(wav, 32);
      if (quad == 0)
        Agg[tm * EMB + colbase + tn * 16 + fm] =
            wav / fmaxf(sqrtf(ssq), 1e-12f);
    }
  __syncthreads();

  // phase 7: out = Agg @ wo + bo
  {
    int d = tid & 127, qp = tid >> 7;
    float boc = bo[d];
    #pragma unroll
    for (int qi2 = 0; qi2 < 2; ++qi2) {
      int q = qp * 2 + qi2;
      float o = 0.f;
      #pragma unroll
      for (int k8 = 0; k8 < 16; ++k8) {
        short8 w8 = *(const short8*)(woT + d * 128 + k8 * 8);
        #pragma unroll
        for (int e = 0; e < 8; ++e)
          o = fmaf(Agg[q * EMB + k8 * 8 + e], bf2f((u16)w8[e]), o);
      }
      out[((size_t)b * NPT + qbase + q) * EMB + d] = o + boc;
    }
  }
}

// ---------------------------------------------------------------- launch
extern "C" void kernel_launch(void* const* d_in, const int* in_sizes, int n_in,
                              void* d_out, int out_size, void* d_ws, size_t ws_size,
                              hipStream_t stream) {
  (void)in_sizes; (void)n_in; (void)out_size; (void)ws_size;
  const float* query = (const float*)d_in[0];
  const float* key_i = (const float*)d_in[1];
  const float* value = (const float*)d_in[2];
  const float* can   = (const float*)d_in[3];
  const float* wq  = (const float*)d_in[4];
  const float* wk  = (const float*)d_in[5];
  const float* wv  = (const float*)d_in[6];
  const float* wo  = (const float*)d_in[7];
  const float* bo  = (const float*)d_in[8];
  const float* p1  = (const float*)d_in[9];
  const float* pb1 = (const float*)d_in[10];
  const float* p2  = (const float*)d_in[11];
  const float* pb2 = (const float*)d_in[12];
  const float* a1  = (const float*)d_in[13];
  const float* ab1 = (const float*)d_in[14];
  const float* a2  = (const float*)d_in[15];
  const float* ab2 = (const float*)d_in[16];

  char* ws = (char*)d_ws;
  u32* pv_ws = (u32*)(ws + 0);            // 4*2048*128 u32 = 4 MiB
  int* idx_ws  = (int*)(ws + 8388608);    // 512 KiB
  u16* wqT = (u16*)(ws + 8912896);
  u16* wkT = (u16*)(ws + 8945664);
  u16* wvT = (u16*)(ws + 8978432);
  u16* p2T = (u16*)(ws + 9011200);
  u16* a1T = (u16*)(ws + 9027584);
  u16* a2T = (u16*)(ws + 9158656);
  u16* woT = (u16*)(ws + 9289728);
  float* out = (float*)d_out;

  k_transpose<<<dim3(7), dim3(256), 0, stream>>>(
      wq, wk, wv, p2, a1, a2, wo, wqT, wkT, wvT, p2T, a1T, a2T, woT);
  k_knn<<<dim3(1024), dim3(256), 0, stream>>>(can, idx_ws);
  k_qkv<<<dim3(256), dim3(256), 0, stream>>>(
      query, key_i, value, wqT, wkT, wvT, pv_ws);
  k_attn<<<dim3(2048), dim3(256), 0, stream>>>(
      can, pv_ws, idx_ws, p1, pb1, p2T, pb2, a1T, ab1, a2T, ab2,
      woT, bo, out);
}

// Round 20
// 284.839 us; speedup vs baseline: 1.7226x; 1.1174x over previous
//
#include <hip/hip_runtime.h>
#include <stdint.h>

typedef unsigned short u16;
typedef unsigned int u32;
typedef unsigned long long u64;
typedef __attribute__((ext_vector_type(8))) short short8;
typedef __attribute__((ext_vector_type(4))) float f32x4;

#define BSZ 4
#define NPT 2048
#define EMB 128
#define PH  64
#define AH  512
#define KNB 16

__device__ __forceinline__ u16 f2bf(float f) {
  union { float f; u32 u; } v; v.f = f;
  u32 r = (v.u >> 16) & 1u;
  v.u += 0x7fffu + r;
  return (u16)(v.u >> 16);
}
__device__ __forceinline__ float bf2f(u16 x) {
  union { u32 u; float f; } v; v.u = ((u32)x) << 16; return v.f;
}

// ---------------------------------------------------------------- transpose
// r20: 40 blocks (was 7 — left 249 CUs idle on uncoalesced strided reads).
// Each block transposes 32 output rows; 32 cols x 8 k-slots per 256 threads.
__global__ __launch_bounds__(256) void k_transpose(
    const float* wq, const float* wk, const float* wv, const float* p2,
    const float* a1, const float* a2, const float* wo,
    u16* wqT, u16* wkT, u16* wvT, u16* p2T, u16* a1T, u16* a2T, u16* woT) {
  int blk = blockIdx.x;
  const float* src; u16* dst; int K, Nn, nbase;
  if (blk < 4)       { src = wq; dst = wqT; K = 128; Nn = 128; nbase = blk * 32; }
  else if (blk < 8)  { src = wk; dst = wkT; K = 128; Nn = 128; nbase = (blk - 4) * 32; }
  else if (blk < 12) { src = wv; dst = wvT; K = 128; Nn = 128; nbase = (blk - 8) * 32; }
  else if (blk < 16) { src = p2; dst = p2T; K = 64;  Nn = 128; nbase = (blk - 12) * 32; }
  else if (blk < 32) { src = a1; dst = a1T; K = 128; Nn = 512; nbase = (blk - 16) * 32; }
  else if (blk < 36) { src = a2; dst = a2T; K = 512; Nn = 128; nbase = (blk - 32) * 32; }
  else               { src = wo; dst = woT; K = 128; Nn = 128; nbase = (blk - 36) * 32; }
  int n = nbase + (threadIdx.x & 31);
  for (int kc = (threadIdx.x >> 5); kc < K / 8; kc += 8) {
    int k0 = kc * 8;
    short8 vv;
    #pragma unroll
    for (int t = 0; t < 8; ++t)
      vv[t] = (short)f2bf(src[(k0 + t) * Nn + n]);
    *(short8*)(dst + n * K + k0) = vv;
  }
}

// ---------------------------------------------------------------- knn
// r20: ONE query per wave (2048 blocks x 4 queries) instead of two serial —
// halves the per-block critical path; pure mapping change. Distance math and
// the extraction loop are BYTE-IDENTICAL to the passing r13/r19 version.
// CURSE LOG: r4/r5/r9 restructures of the extraction loop all produced
// identical wrong output (absmax 0.71875) — only this r2 idiom passes;
// scheduling/memory-source changes at most.
__device__ __forceinline__ u32 f2sort(float f) {
  union { float f; u32 u; } v; v.f = f;
  return v.u ^ ((v.u >> 31) ? 0xFFFFFFFFu : 0x80000000u);
}

__global__ __launch_bounds__(256) void k_knn(const float* __restrict__ can,
                                             int* __restrict__ idx_out) {
  __shared__ float dists[4][NPT];
  int b = blockIdx.x >> 9;      // 2048 blocks: 512 per batch
  int qblk = blockIdx.x & 511;  // 4 queries per block, one per wave
  const float* cb = can + (size_t)b * NPT * 3;
  int wave = threadIdx.x >> 6, lane = threadIdx.x & 63;
  float* dw = dists[wave];
  {
    int i = qblk * 4 + wave;
    float xi = cb[i * 3 + 0], yi = cb[i * 3 + 1], zi = cb[i * 3 + 2];
    float sqi = __fadd_rn(__fadd_rn(__fmul_rn(xi, xi), __fmul_rn(yi, yi)),
                          __fmul_rn(zi, zi));
    u64 lmin = ~0ull;
    #pragma unroll 4
    for (int c = 0; c < NPT / 64; ++c) {
      int j = c * 64 + lane;
      const float* pj = cb + j * 3;
      float xj = pj[0], yj = pj[1], zj = pj[2];
      float sqj = __fadd_rn(__fadd_rn(__fmul_rn(xj, xj), __fmul_rn(yj, yj)),
                            __fmul_rn(zj, zj));
      float nn = __fadd_rn(__fadd_rn(__fmul_rn(xi, xj), __fmul_rn(yi, yj)),
                           __fmul_rn(zi, zj));
      float dist = __fadd_rn(__fsub_rn(sqi, __fmul_rn(2.0f, nn)), sqj);
      dw[j] = dist;
      u64 key = (((u64)f2sort(dist)) << 32) | (u32)j;
      lmin = key < lmin ? key : lmin;
    }
    #pragma unroll 1
    for (int r = 0; r < KNB; ++r) {
      u64 g = lmin;
      #pragma unroll
      for (int off = 32; off > 0; off >>= 1) {
        u64 o = __shfl_xor(g, off);
        g = o < g ? o : g;
      }
      int jw = (int)(u32)(g & 0xffffffffull);
      if (lane == 0) idx_out[((size_t)b * NPT + i) * KNB + r] = jw;
      if ((jw & 63) == lane) {
        union { u32 u; float f; } inf; inf.u = 0x7f800000u;
        dw[jw] = inf.f;
        lmin = ~0ull;
        #pragma unroll
        for (int c = 0; c < NPT / 64; ++c) {
          int j = c * 64 + lane;
          u64 key = (((u64)f2sort(dw[j])) << 32) | (u32)j;
          lmin = key < lmin ? key : lmin;
        }
      }
    }
  }
}

// ---------------------------------------------------------------- qkv
// 256 blocks x 32 rows. pv[point][col] = bf16(q@wq-k@wk) | bf16(v@wv)<<16.
__device__ __forceinline__ void qkv_gemm32(const u16* At, const u16* wT,
                                           int colbase, int fm, int quad,
                                           f32x4 acc[2][2]) {
  #pragma unroll
  for (int tn = 0; tn < 2; ++tn)
    #pragma unroll
    for (int tm = 0; tm < 2; ++tm) acc[tn][tm] = (f32x4){0.f, 0.f, 0.f, 0.f};
  #pragma unroll
  for (int ks = 0; ks < 4; ++ks) {
    int k0 = ks * 32 + quad * 8;
    short8 bfr0 = *(const short8*)(wT + (colbase + fm) * 128 + k0);
    short8 bfr1 = *(const short8*)(wT + (colbase + 16 + fm) * 128 + k0);
    #pragma unroll
    for (int tm = 0; tm < 2; ++tm) {
      short8 afr = *(const short8*)(At + (tm * 16 + fm) * 136 + k0);
      acc[0][tm] = __builtin_amdgcn_mfma_f32_16x16x32_bf16(afr, bfr0, acc[0][tm], 0, 0, 0);
      acc[1][tm] = __builtin_amdgcn_mfma_f32_16x16x32_bf16(afr, bfr1, acc[1][tm], 0, 0, 0);
    }
  }
}

__device__ __forceinline__ void qkv_stage32(u16* At, const float* src, int rbase, int tid) {
  #pragma unroll
  for (int rep = 0; rep < 2; ++rep) {
    int linear = tid + 256 * rep;
    int row = linear >> 4;
    int c16 = linear & 15;
    const float* sp = src + (size_t)(rbase + row) * 128 + c16 * 8;
    f32x4 a = *(const f32x4*)(sp);
    f32x4 b = *(const f32x4*)(sp + 4);
    short8 vv;
    vv[0] = (short)f2bf(a[0]); vv[1] = (short)f2bf(a[1]);
    vv[2] = (short)f2bf(a[2]); vv[3] = (short)f2bf(a[3]);
    vv[4] = (short)f2bf(b[0]); vv[5] = (short)f2bf(b[1]);
    vv[6] = (short)f2bf(b[2]); vv[7] = (short)f2bf(b[3]);
    *(short8*)(At + row * 136 + c16 * 8) = vv;
  }
}

__global__ __launch_bounds__(256) void k_qkv(
    const float* __restrict__ query, const float* __restrict__ key,
    const float* __restrict__ value,
    const u16* __restrict__ wqT, const u16* __restrict__ wkT,
    const u16* __restrict__ wvT,
    u32* __restrict__ pv_out) {
  __shared__ __align__(16) u16 At[32 * 136];
  int tid = threadIdx.x;
  int rbase = blockIdx.x * 32;
  int lane = tid & 63, wave = tid >> 6;
  int fm = lane & 15, quad = lane >> 4;
  int colbase = wave * 32;
  f32x4 accq[2][2], acck[2][2];

  qkv_stage32(At, query, rbase, tid);
  __syncthreads();
  qkv_gemm32(At, wqT, colbase, fm, quad, accq);
  __syncthreads();
  qkv_stage32(At, key, rbase, tid);
  __syncthreads();
  qkv_gemm32(At, wkT, colbase, fm, quad, acck);
  u32 qk2[2][4];
  #pragma unroll
  for (int tm = 0; tm < 2; ++tm)
    #pragma unroll
    for (int r = 0; r < 4; ++r)
      qk2[tm][r] = (u32)f2bf(accq[0][tm][r] - acck[0][tm][r]) |
                   (((u32)f2bf(accq[1][tm][r] - acck[1][tm][r])) << 16);
  __syncthreads();
  qkv_stage32(At, value, rbase, tid);
  __syncthreads();
  qkv_gemm32(At, wvT, colbase, fm, quad, accq);
  #pragma unroll
  for (int tn = 0; tn < 2; ++tn) {
    int col = colbase + tn * 16 + fm;
    #pragma unroll
    for (int tm = 0; tm < 2; ++tm)
      #pragma unroll
      for (int r = 0; r < 4; ++r) {
        int row = tm * 16 + quad * 4 + r;
        u32 qkb = tn == 0 ? (qk2[tm][r] & 0xffffu) : (qk2[tm][r] >> 16);
        u32 pack = qkb | (((u32)f2bf(accq[tn][tm][r])) << 16);
        pv_out[(size_t)(rbase + row) * 128 + col] = pack;
      }
  }
}

// ---------------------------------------------------------------- fused attention
// EXACT r16 k_attn (best measured: ~139us). r17 (wave-parallel) 4x'd weight
// loads -> 335us; r18 (Hs dbuf + a-frag prefetch) overflowed the 3-block
// LDS line AND spilled -> 164us. FROZEN: (256,3), 39KB LDS, no extra
// register hoards.
#define XT_LD 136

__global__ __launch_bounds__(256, 3) void k_attn(
    const float* __restrict__ can,
    const u32* __restrict__ pv_g,
    const int* __restrict__ idx_g,
    const float* __restrict__ p1, const float* __restrict__ pb1,
    const u16* __restrict__ p2T, const float* __restrict__ pb2,
    const u16* __restrict__ a1T, const float* __restrict__ ab1,
    const u16* __restrict__ a2T, const float* __restrict__ ab2,
    const u16* __restrict__ woT, const float* __restrict__ bo,
    float* __restrict__ out) {
  __shared__ __align__(16) char smem[39168];
  u16* Xt = (u16*)(smem);              // [64][136] bf16
  u16* Hs = (u16*)(smem + 17408);      // [64][136] bf16
  u16* R1 = (u16*)(smem + 17408);      // [64][72] bf16 (dead before Hs)
  float* Red1 = (float*)(smem + 34816); // [4][64] f32 row-max partials
  float* Red2 = (float*)(smem + 35840); // [4][64] f32 row-sum partials
  float* Agg = (float*)(smem + 36864); // [4][128] f32
  int* Idx = (int*)(smem + 38912);     // [64]

  const int b = blockIdx.x >> 9;
  const int qbase = (blockIdx.x & 511) * 4;
  const int tid = threadIdx.x;
  const int lane = tid & 63, wave = tid >> 6;
  const int fm = lane & 15, quad = lane >> 4;
  const int colbase = wave * 32;

  if (tid < 64) Idx[tid] = idx_g[((size_t)b * NPT + qbase) * KNB + tid];
  __syncthreads();

  // prefetch the 32 pv gathers NOW; latency hides under phase 1 + MFMA
  u32 pvld[2][4][4];
  #pragma unroll
  for (int tn = 0; tn < 2; ++tn) {
    int col = colbase + tn * 16 + fm;
    #pragma unroll
    for (int tm = 0; tm < 4; ++tm)
      #pragma unroll
      for (int r = 0; r < 4; ++r) {
        int row = tm * 16 + quad * 4 + r;
        int j = Idx[row];
        pvld[tn][tm][r] = pv_g[((size_t)b * NPT + j) * EMB + col];
      }
  }

  // phase 1: R1 = relu(rel_pos @ p1 + pb1), bf16 (4 threads per row).
  {
    int row = tid >> 2, part = tid & 3;
    int j = Idx[row];
    int qi = qbase + (row >> 4);
    const float* cb = can + (size_t)b * NPT * 3;
    float r0 = cb[j * 3 + 0] - cb[qi * 3 + 0];
    float r1 = cb[j * 3 + 1] - cb[qi * 3 + 1];
    float r2 = cb[j * 3 + 2] - cb[qi * 3 + 2];
    #pragma unroll
    for (int hp = 0; hp < 8; ++hp) {
      int cp = part + 4 * hp;
      u32 pack = 0;
      #pragma unroll
      for (int e = 0; e < 2; ++e) {
        int hh = cp * 2 + e;
        float s = r0 * p1[hh];
        s = fmaf(r1, p1[PH + hh], s);
        s = fmaf(r2, p1[2 * PH + hh], s);
        s += pb1[hh];
        s = fmaxf(s, 0.0f);
        pack |= ((u32)f2bf(s)) << (16 * e);
      }
      *(u32*)(R1 + row * 72 + cp * 2) = pack;
    }
  }
  __syncthreads();

  // phase 2: rpe = R1@p2 + pb2 (MFMA); combine with prefetched pv:
  // Xt = qk+rpe (LDS), vp = v+rpe (packed bf16 registers)
  u32 vp[4][4];
  {
    f32x4 acc[2][4];
    #pragma unroll
    for (int tn = 0; tn < 2; ++tn)
      #pragma unroll
      for (int tm = 0; tm < 4; ++tm) acc[tn][tm] = (f32x4){0.f, 0.f, 0.f, 0.f};
    #pragma unroll
    for (int ks = 0; ks < 2; ++ks) {
      int k0 = ks * 32 + quad * 8;
      short8 bfr0 = *(const short8*)(p2T + (colbase + fm) * PH + k0);
      short8 bfr1 = *(const short8*)(p2T + (colbase + 16 + fm) * PH + k0);
      #pragma unroll
      for (int tm = 0; tm < 4; ++tm) {
        short8 afr = *(const short8*)(R1 + (tm * 16 + fm) * 72 + k0);
        acc[0][tm] = __builtin_amdgcn_mfma_f32_16x16x32_bf16(afr, bfr0, acc[0][tm], 0, 0, 0);
        acc[1][tm] = __builtin_amdgcn_mfma_f32_16x16x32_bf16(afr, bfr1, acc[1][tm], 0, 0, 0);
      }
    }
    #pragma unroll
    for (int tn = 0; tn < 2; ++tn) {
      int col = colbase + tn * 16 + fm;
      float pb2c = pb2[col];
      #pragma unroll
      for (int tm = 0; tm < 4; ++tm)
        #pragma unroll
        for (int r = 0; r < 4; ++r) {
          int row = tm * 16 + quad * 4 + r;
          float rpe = acc[tn][tm][r] + pb2c;
          u32 w = pvld[tn][tm][r];
          Xt[row * XT_LD + col] = f2bf(bf2f((u16)(w & 0xffffu)) + rpe);
          u32 vb = (u32)f2bf(bf2f((u16)(w >> 16)) + rpe);
          if (tn == 0) vp[tm][r] = vb; else vp[tm][r] |= vb << 16;
        }
    }
  }
  __syncthreads();

  // phase 3: S = relu(X@a1+ab1)@a2, 4 chunks of 128 hidden cols
  f32x4 accS[2][4];
  #pragma unroll
  for (int tn = 0; tn < 2; ++tn)
    #pragma unroll
    for (int tm = 0; tm < 4; ++tm) accS[tn][tm] = (f32x4){0.f, 0.f, 0.f, 0.f};
  #pragma unroll 1
  for (int c = 0; c < 4; ++c) {
    f32x4 acc1[2][4];
    #pragma unroll
    for (int tn = 0; tn < 2; ++tn)
      #pragma unroll
      for (int tm = 0; tm < 4; ++tm) acc1[tn][tm] = (f32x4){0.f, 0.f, 0.f, 0.f};
    #pragma unroll
    for (int ks = 0; ks < 4; ++ks) {
      int k0 = ks * 32 + quad * 8;
      short8 bfr0 = *(const short8*)(a1T + (c * 128 + colbase + fm) * 128 + k0);
      short8 bfr1 = *(const short8*)(a1T + (c * 128 + colbase + 16 + fm) * 128 + k0);
      #pragma unroll
      for (int tm = 0; tm < 4; ++tm) {
        short8 afr = *(const short8*)(Xt + (tm * 16 + fm) * XT_LD + k0);
        acc1[0][tm] = __builtin_amdgcn_mfma_f32_16x16x32_bf16(afr, bfr0, acc1[0][tm], 0, 0, 0);
        acc1[1][tm] = __builtin_amdgcn_mfma_f32_16x16x32_bf16(afr, bfr1, acc1[1][tm], 0, 0, 0);
      }
    }
    #pragma unroll
    for (int tn = 0; tn < 2; ++tn) {
      int lcol = colbase + tn * 16 + fm;
      float ab1c = ab1[c * 128 + lcol];
      #pragma unroll
      for (int tm = 0; tm < 4; ++tm)
        #pragma unroll
        for (int r = 0; r < 4; ++r) {
          int row = tm * 16 + quad * 4 + r;
          Hs[row * XT_LD + lcol] = f2bf(fmaxf(acc1[tn][tm][r] + ab1c, 0.0f));
        }
    }
    __syncthreads();
    #pragma unroll
    for (int ks = 0; ks < 4; ++ks) {
      int k0 = ks * 32 + quad * 8;
      short8 bfr0 = *(const short8*)(a2T + (colbase + fm) * AH + c * 128 + k0);
      short8 bfr1 = *(const short8*)(a2T + (colbase + 16 + fm) * AH + c * 128 + k0);
      #pragma unroll
      for (int tm = 0; tm < 4; ++tm) {
        short8 afr = *(const short8*)(Hs + (tm * 16 + fm) * XT_LD + k0);
        accS[0][tm] = __builtin_amdgcn_mfma_f32_16x16x32_bf16(afr, bfr0, accS[0][tm], 0, 0, 0);
        accS[1][tm] = __builtin_amdgcn_mfma_f32_16x16x32_bf16(afr, bfr1, accS[1][tm], 0, 0, 0);
      }
    }
    __syncthreads();
  }

  // phase 4: softmax over 128 features per row, register-resident.
  {
    float ab2c0 = ab2[colbase + fm];
    float ab2c1 = ab2[colbase + 16 + fm];
    float rm[4][4];
    #pragma unroll
    for (int tm = 0; tm < 4; ++tm)
      #pragma unroll
      for (int r = 0; r < 4; ++r) {
        accS[0][tm][r] += ab2c0;
        accS[1][tm][r] += ab2c1;
        rm[tm][r] = fmaxf(accS[0][tm][r], accS[1][tm][r]);
      }
    #pragma unroll
    for (int off = 1; off <= 8; off <<= 1)
      #pragma unroll
      for (int tm = 0; tm < 4; ++tm)
        #pragma unroll
        for (int r = 0; r < 4; ++r)
          rm[tm][r] = fmaxf(rm[tm][r], __shfl_xor(rm[tm][r], off));
    if (fm == 0) {
      #pragma unroll
      for (int tm = 0; tm < 4; ++tm)
        #pragma unroll
        for (int r = 0; r < 4; ++r)
          Red1[wave * 64 + tm * 16 + quad * 4 + r] = rm[tm][r];
    }
    __syncthreads();
    #pragma unroll
    for (int tm = 0; tm < 4; ++tm)
      #pragma unroll
      for (int r = 0; r < 4; ++r) {
        int row = tm * 16 + quad * 4 + r;
        float m = fmaxf(fmaxf(Red1[row], Red1[64 + row]),
                        fmaxf(Red1[128 + row], Red1[192 + row]));
        float e0 = __expf(accS[0][tm][r] - m);
        float e1 = __expf(accS[1][tm][r] - m);
        accS[0][tm][r] = e0;
        accS[1][tm][r] = e1;
        rm[tm][r] = e0 + e1;
      }
    #pragma unroll
    for (int off = 1; off <= 8; off <<= 1)
      #pragma unroll
      for (int tm = 0; tm < 4; ++tm)
        #pragma unroll
        for (int r = 0; r < 4; ++r)
          rm[tm][r] += __shfl_xor(rm[tm][r], off);
    if (fm == 0) {
      #pragma unroll
      for (int tm = 0; tm < 4; ++tm)
        #pragma unroll
        for (int r = 0; r < 4; ++r)
          Red2[wave * 64 + tm * 16 + quad * 4 + r] = rm[tm][r];
    }
    __syncthreads();
    #pragma unroll
    for (int tm = 0; tm < 4; ++tm)
      #pragma unroll
      for (int r = 0; r < 4; ++r) {
        int row = tm * 16 + quad * 4 + r;
        float sum = (Red2[row] + Red2[64 + row]) +
                    (Red2[128 + row] + Red2[192 + row]);
        float inv = 1.0f / sum;   // sum >= exp(0) = 1
        accS[0][tm][r] *= inv;
        accS[1][tm][r] *= inv;
      }
  }

  // phase 5: L2-norm over the 16 neighbors + aggregate, register-resident.
  #pragma unroll
  for (int tn = 0; tn < 2; ++tn)
    #pragma unroll
    for (int tm = 0; tm < 4; ++tm) {
      float ssq = 0.f, wav = 0.f;
      #pragma unroll
      for (int r = 0; r < 4; ++r) {
        float a = accS[tn][tm][r];
        u16 vb = (u16)(tn == 0 ? (vp[tm][r] & 0xffffu) : (vp[tm][r] >> 16));
        ssq = fmaf(a, a, ssq);
        wav = fmaf(a, bf2f(vb), wav);
      }
      ssq += __shfl_xor(ssq, 16); ssq += __shfl_xor(ssq, 32);
      wav += __shfl_xor(wav, 16); wav += __shfl_xor(wav, 32);
      if (quad == 0)
        Agg[tm * EMB + colbase + tn * 16 + fm] =
            wav / fmaxf(sqrtf(ssq), 1e-12f);
    }
  __syncthreads();

  // phase 7: out = Agg @ wo + bo
  {
    int d = tid & 127, qp = tid >> 7;
    float boc = bo[d];
    #pragma unroll
    for (int qi2 = 0; qi2 < 2; ++qi2) {
      int q = qp * 2 + qi2;
      float o = 0.f;
      #pragma unroll
      for (int k8 = 0; k8 < 16; ++k8) {
        short8 w8 = *(const short8*)(woT + d * 128 + k8 * 8);
        #pragma unroll
        for (int e = 0; e < 8; ++e)
          o = fmaf(Agg[q * EMB + k8 * 8 + e], bf2f((u16)w8[e]), o);
      }
      out[((size_t)b * NPT + qbase + q) * EMB + d] = o + boc;
    }
  }
}

// ---------------------------------------------------------------- launch
extern "C" void kernel_launch(void* const* d_in, const int* in_sizes, int n_in,
                              void* d_out, int out_size, void* d_ws, size_t ws_size,
                              hipStream_t stream) {
  (void)in_sizes; (void)n_in; (void)out_size; (void)ws_size;
  const float* query = (const float*)d_in[0];
  const float* key_i = (const float*)d_in[1];
  const float* value = (const float*)d_in[2];
  const float* can   = (const float*)d_in[3];
  const float* wq  = (const float*)d_in[4];
  const float* wk  = (const float*)d_in[5];
  const float* wv  = (const float*)d_in[6];
  const float* wo  = (const float*)d_in[7];
  const float* bo  = (const float*)d_in[8];
  const float* p1  = (const float*)d_in[9];
  const float* pb1 = (const float*)d_in[10];
  const float* p2  = (const float*)d_in[11];
  const float* pb2 = (const float*)d_in[12];
  const float* a1  = (const float*)d_in[13];
  const float* ab1 = (const float*)d_in[14];
  const float* a2  = (const float*)d_in[15];
  const float* ab2 = (const float*)d_in[16];

  char* ws = (char*)d_ws;
  u32* pv_ws = (u32*)(ws + 0);            // 4*2048*128 u32 = 4 MiB
  int* idx_ws  = (int*)(ws + 8388608);    // 512 KiB
  u16* wqT = (u16*)(ws + 8912896);
  u16* wkT = (u16*)(ws + 8945664);
  u16* wvT = (u16*)(ws + 8978432);
  u16* p2T = (u16*)(ws + 9011200);
  u16* a1T = (u16*)(ws + 9027584);
  u16* a2T = (u16*)(ws + 9158656);
  u16* woT = (u16*)(ws + 9289728);
  float* out = (float*)d_out;

  k_transpose<<<dim3(40), dim3(256), 0, stream>>>(
      wq, wk, wv, p2, a1, a2, wo, wqT, wkT, wvT, p2T, a1T, a2T, woT);
  k_knn<<<dim3(2048), dim3(256), 0, stream>>>(can, idx_ws);
  k_qkv<<<dim3(256), dim3(256), 0, stream>>>(
      query, key_i, value, wqT, wkT, wvT, pv_ws);
  k_attn<<<dim3(2048), dim3(256), 0, stream>>>(
      can, pv_ws, idx_ws, p1, pb1, p2T, pb2, a1T, ab1, a2T, ab2,
      woT, bo, out);
}

// Round 21
// 277.319 us; speedup vs baseline: 1.7693x; 1.0271x over previous
//
#include <hip/hip_runtime.h>
#include <stdint.h>

typedef unsigned short u16;
typedef unsigned int u32;
typedef unsigned long long u64;
typedef __attribute__((ext_vector_type(8))) short short8;
typedef __attribute__((ext_vector_type(4))) float f32x4;

#define BSZ 4
#define NPT 2048
#define EMB 128
#define PH  64
#define AH  512
#define KNB 16

__device__ __forceinline__ u16 f2bf(float f) {
  union { float f; u32 u; } v; v.f = f;
  u32 r = (v.u >> 16) & 1u;
  v.u += 0x7fffu + r;
  return (u16)(v.u >> 16);
}
__device__ __forceinline__ float bf2f(u16 x) {
  union { u32 u; float f; } v; v.u = ((u32)x) << 16; return v.f;
}

// ---------------------------------------------------------------- transpose
// 40 blocks; each transposes 32 output rows (32 cols x 8 k-slots / 256 thr).
__global__ __launch_bounds__(256) void k_transpose(
    const float* wq, const float* wk, const float* wv, const float* p2,
    const float* a1, const float* a2, const float* wo,
    u16* wqT, u16* wkT, u16* wvT, u16* p2T, u16* a1T, u16* a2T, u16* woT) {
  int blk = blockIdx.x;
  const float* src; u16* dst; int K, Nn, nbase;
  if (blk < 4)       { src = wq; dst = wqT; K = 128; Nn = 128; nbase = blk * 32; }
  else if (blk < 8)  { src = wk; dst = wkT; K = 128; Nn = 128; nbase = (blk - 4) * 32; }
  else if (blk < 12) { src = wv; dst = wvT; K = 128; Nn = 128; nbase = (blk - 8) * 32; }
  else if (blk < 16) { src = p2; dst = p2T; K = 64;  Nn = 128; nbase = (blk - 12) * 32; }
  else if (blk < 32) { src = a1; dst = a1T; K = 128; Nn = 512; nbase = (blk - 16) * 32; }
  else if (blk < 36) { src = a2; dst = a2T; K = 512; Nn = 128; nbase = (blk - 32) * 32; }
  else               { src = wo; dst = woT; K = 128; Nn = 128; nbase = (blk - 36) * 32; }
  int n = nbase + (threadIdx.x & 31);
  for (int kc = (threadIdx.x >> 5); kc < K / 8; kc += 8) {
    int k0 = kc * 8;
    short8 vv;
    #pragma unroll
    for (int t = 0; t < 8; ++t)
      vv[t] = (short)f2bf(src[(k0 + t) * Nn + n]);
    *(short8*)(dst + n * K + k0) = vv;
  }
}

// ---------------------------------------------------------------- fused knn + qkv
// r21: knn (latency-bound: LDS scans/shuffles, 0 MFMA) and qkv (MFMA-bound)
// are data-independent with complementary pipe usage — fused into one
// dispatch so they co-schedule. qkv blocks FIRST (0..255) so they start
// while the 2048 knn blocks stream in. Bodies verbatim from r20 (identical
// bits). LDS union = knn's 32KB -> 5 blocks/CU unchanged.
// CURSE LOG (knn): r4/r5/r9 restructures of the extraction loop all
// produced identical wrong output (absmax 0.71875) — only the r2 idiom
// passes; scheduling/mapping changes at most.
__device__ __forceinline__ u32 f2sort(float f) {
  union { float f; u32 u; } v; v.f = f;
  return v.u ^ ((v.u >> 31) ? 0xFFFFFFFFu : 0x80000000u);
}

__device__ __forceinline__ void knn_body(char* sm, int bid,
                                         const float* __restrict__ can,
                                         int* __restrict__ idx_out) {
  float (*dists)[NPT] = (float (*)[NPT])sm;
  int b = bid >> 9;      // 2048 blocks: 512 per batch
  int qblk = bid & 511;  // 4 queries per block, one per wave
  const float* cb = can + (size_t)b * NPT * 3;
  int wave = threadIdx.x >> 6, lane = threadIdx.x & 63;
  float* dw = dists[wave];
  {
    int i = qblk * 4 + wave;
    float xi = cb[i * 3 + 0], yi = cb[i * 3 + 1], zi = cb[i * 3 + 2];
    float sqi = __fadd_rn(__fadd_rn(__fmul_rn(xi, xi), __fmul_rn(yi, yi)),
                          __fmul_rn(zi, zi));
    u64 lmin = ~0ull;
    #pragma unroll 4
    for (int c = 0; c < NPT / 64; ++c) {
      int j = c * 64 + lane;
      const float* pj = cb + j * 3;
      float xj = pj[0], yj = pj[1], zj = pj[2];
      float sqj = __fadd_rn(__fadd_rn(__fmul_rn(xj, xj), __fmul_rn(yj, yj)),
                            __fmul_rn(zj, zj));
      float nn = __fadd_rn(__fadd_rn(__fmul_rn(xi, xj), __fmul_rn(yi, yj)),
                           __fmul_rn(zi, zj));
      float dist = __fadd_rn(__fsub_rn(sqi, __fmul_rn(2.0f, nn)), sqj);
      dw[j] = dist;
      u64 key = (((u64)f2sort(dist)) << 32) | (u32)j;
      lmin = key < lmin ? key : lmin;
    }
    #pragma unroll 1
    for (int r = 0; r < KNB; ++r) {
      u64 g = lmin;
      #pragma unroll
      for (int off = 32; off > 0; off >>= 1) {
        u64 o = __shfl_xor(g, off);
        g = o < g ? o : g;
      }
      int jw = (int)(u32)(g & 0xffffffffull);
      if (lane == 0) idx_out[((size_t)b * NPT + i) * KNB + r] = jw;
      if ((jw & 63) == lane) {
        union { u32 u; float f; } inf; inf.u = 0x7f800000u;
        dw[jw] = inf.f;
        lmin = ~0ull;
        #pragma unroll
        for (int c = 0; c < NPT / 64; ++c) {
          int j = c * 64 + lane;
          u64 key = (((u64)f2sort(dw[j])) << 32) | (u32)j;
          lmin = key < lmin ? key : lmin;
        }
      }
    }
  }
}

__device__ __forceinline__ void qkv_gemm32(const u16* At, const u16* wT,
                                           int colbase, int fm, int quad,
                                           f32x4 acc[2][2]) {
  #pragma unroll
  for (int tn = 0; tn < 2; ++tn)
    #pragma unroll
    for (int tm = 0; tm < 2; ++tm) acc[tn][tm] = (f32x4){0.f, 0.f, 0.f, 0.f};
  #pragma unroll
  for (int ks = 0; ks < 4; ++ks) {
    int k0 = ks * 32 + quad * 8;
    short8 bfr0 = *(const short8*)(wT + (colbase + fm) * 128 + k0);
    short8 bfr1 = *(const short8*)(wT + (colbase + 16 + fm) * 128 + k0);
    #pragma unroll
    for (int tm = 0; tm < 2; ++tm) {
      short8 afr = *(const short8*)(At + (tm * 16 + fm) * 136 + k0);
      acc[0][tm] = __builtin_amdgcn_mfma_f32_16x16x32_bf16(afr, bfr0, acc[0][tm], 0, 0, 0);
      acc[1][tm] = __builtin_amdgcn_mfma_f32_16x16x32_bf16(afr, bfr1, acc[1][tm], 0, 0, 0);
    }
  }
}

__device__ __forceinline__ void qkv_stage32(u16* At, const float* src, int rbase, int tid) {
  #pragma unroll
  for (int rep = 0; rep < 2; ++rep) {
    int linear = tid + 256 * rep;
    int row = linear >> 4;
    int c16 = linear & 15;
    const float* sp = src + (size_t)(rbase + row) * 128 + c16 * 8;
    f32x4 a = *(const f32x4*)(sp);
    f32x4 b = *(const f32x4*)(sp + 4);
    short8 vv;
    vv[0] = (short)f2bf(a[0]); vv[1] = (short)f2bf(a[1]);
    vv[2] = (short)f2bf(a[2]); vv[3] = (short)f2bf(a[3]);
    vv[4] = (short)f2bf(b[0]); vv[5] = (short)f2bf(b[1]);
    vv[6] = (short)f2bf(b[2]); vv[7] = (short)f2bf(b[3]);
    *(short8*)(At + row * 136 + c16 * 8) = vv;
  }
}

__device__ __forceinline__ void qkv_body(char* sm, int bid,
    const float* __restrict__ query, const float* __restrict__ key,
    const float* __restrict__ value,
    const u16* __restrict__ wqT, const u16* __restrict__ wkT,
    const u16* __restrict__ wvT, u32* __restrict__ pv_out) {
  u16* At = (u16*)sm;
  int tid = threadIdx.x;
  int rbase = bid * 32;
  int lane = tid & 63, wave = tid >> 6;
  int fm = lane & 15, quad = lane >> 4;
  int colbase = wave * 32;
  f32x4 accq[2][2], acck[2][2];

  qkv_stage32(At, query, rbase, tid);
  __syncthreads();
  qkv_gemm32(At, wqT, colbase, fm, quad, accq);
  __syncthreads();
  qkv_stage32(At, key, rbase, tid);
  __syncthreads();
  qkv_gemm32(At, wkT, colbase, fm, quad, acck);
  u32 qk2[2][4];
  #pragma unroll
  for (int tm = 0; tm < 2; ++tm)
    #pragma unroll
    for (int r = 0; r < 4; ++r)
      qk2[tm][r] = (u32)f2bf(accq[0][tm][r] - acck[0][tm][r]) |
                   (((u32)f2bf(accq[1][tm][r] - acck[1][tm][r])) << 16);
  __syncthreads();
  qkv_stage32(At, value, rbase, tid);
  __syncthreads();
  qkv_gemm32(At, wvT, colbase, fm, quad, accq);
  #pragma unroll
  for (int tn = 0; tn < 2; ++tn) {
    int col = colbase + tn * 16 + fm;
    #pragma unroll
    for (int tm = 0; tm < 2; ++tm)
      #pragma unroll
      for (int r = 0; r < 4; ++r) {
        int row = tm * 16 + quad * 4 + r;
        u32 qkb = tn == 0 ? (qk2[tm][r] & 0xffffu) : (qk2[tm][r] >> 16);
        u32 pack = qkb | (((u32)f2bf(accq[tn][tm][r])) << 16);
        pv_out[(size_t)(rbase + row) * 128 + col] = pack;
      }
  }
}

__global__ __launch_bounds__(256) void k_fused(
    const float* __restrict__ can, int* __restrict__ idx_out,
    const float* __restrict__ query, const float* __restrict__ key,
    const float* __restrict__ value,
    const u16* __restrict__ wqT, const u16* __restrict__ wkT,
    const u16* __restrict__ wvT, u32* __restrict__ pv_out) {
  __shared__ __align__(16) char sm[32768];
  if (blockIdx.x < 256)
    qkv_body(sm, blockIdx.x, query, key, value, wqT, wkT, wvT, pv_out);
  else
    knn_body(sm, blockIdx.x - 256, can, idx_out);
}

// ---------------------------------------------------------------- fused attention
// EXACT r16 k_attn (best measured: ~138us). r17 (wave-parallel) 4x'd weight
// loads -> 335us; r18 (Hs dbuf + a-frag prefetch) overflowed the 3-block
// LDS line AND spilled -> 164us. FROZEN: (256,3), 39KB LDS, no extra
// register hoards.
#define XT_LD 136

__global__ __launch_bounds__(256, 3) void k_attn(
    const float* __restrict__ can,
    const u32* __restrict__ pv_g,
    const int* __restrict__ idx_g,
    const float* __restrict__ p1, const float* __restrict__ pb1,
    const u16* __restrict__ p2T, const float* __restrict__ pb2,
    const u16* __restrict__ a1T, const float* __restrict__ ab1,
    const u16* __restrict__ a2T, const float* __restrict__ ab2,
    const u16* __restrict__ woT, const float* __restrict__ bo,
    float* __restrict__ out) {
  __shared__ __align__(16) char smem[39168];
  u16* Xt = (u16*)(smem);              // [64][136] bf16
  u16* Hs = (u16*)(smem + 17408);      // [64][136] bf16
  u16* R1 = (u16*)(smem + 17408);      // [64][72] bf16 (dead before Hs)
  float* Red1 = (float*)(smem + 34816); // [4][64] f32 row-max partials
  float* Red2 = (float*)(smem + 35840); // [4][64] f32 row-sum partials
  float* Agg = (float*)(smem + 36864); // [4][128] f32
  int* Idx = (int*)(smem + 38912);     // [64]

  const int b = blockIdx.x >> 9;
  const int qbase = (blockIdx.x & 511) * 4;
  const int tid = threadIdx.x;
  const int lane = tid & 63, wave = tid >> 6;
  const int fm = lane & 15, quad = lane >> 4;
  const int colbase = wave * 32;

  if (tid < 64) Idx[tid] = idx_g[((size_t)b * NPT + qbase) * KNB + tid];
  __syncthreads();

  // prefetch the 32 pv gathers NOW; latency hides under phase 1 + MFMA
  u32 pvld[2][4][4];
  #pragma unroll
  for (int tn = 0; tn < 2; ++tn) {
    int col = colbase + tn * 16 + fm;
    #pragma unroll
    for (int tm = 0; tm < 4; ++tm)
      #pragma unroll
      for (int r = 0; r < 4; ++r) {
        int row = tm * 16 + quad * 4 + r;
        int j = Idx[row];
        pvld[tn][tm][r] = pv_g[((size_t)b * NPT + j) * EMB + col];
      }
  }

  // phase 1: R1 = relu(rel_pos @ p1 + pb1), bf16 (4 threads per row).
  {
    int row = tid >> 2, part = tid & 3;
    int j = Idx[row];
    int qi = qbase + (row >> 4);
    const float* cb = can + (size_t)b * NPT * 3;
    float r0 = cb[j * 3 + 0] - cb[qi * 3 + 0];
    float r1 = cb[j * 3 + 1] - cb[qi * 3 + 1];
    float r2 = cb[j * 3 + 2] - cb[qi * 3 + 2];
    #pragma unroll
    for (int hp = 0; hp < 8; ++hp) {
      int cp = part + 4 * hp;
      u32 pack = 0;
      #pragma unroll
      for (int e = 0; e < 2; ++e) {
        int hh = cp * 2 + e;
        float s = r0 * p1[hh];
        s = fmaf(r1, p1[PH + hh], s);
        s = fmaf(r2, p1[2 * PH + hh], s);
        s += pb1[hh];
        s = fmaxf(s, 0.0f);
        pack |= ((u32)f2bf(s)) << (16 * e);
      }
      *(u32*)(R1 + row * 72 + cp * 2) = pack;
    }
  }
  __syncthreads();

  // phase 2: rpe = R1@p2 + pb2 (MFMA); combine with prefetched pv:
  // Xt = qk+rpe (LDS), vp = v+rpe (packed bf16 registers)
  u32 vp[4][4];
  {
    f32x4 acc[2][4];
    #pragma unroll
    for (int tn = 0; tn < 2; ++tn)
      #pragma unroll
      for (int tm = 0; tm < 4; ++tm) acc[tn][tm] = (f32x4){0.f, 0.f, 0.f, 0.f};
    #pragma unroll
    for (int ks = 0; ks < 2; ++ks) {
      int k0 = ks * 32 + quad * 8;
      short8 bfr0 = *(const short8*)(p2T + (colbase + fm) * PH + k0);
      short8 bfr1 = *(const short8*)(p2T + (colbase + 16 + fm) * PH + k0);
      #pragma unroll
      for (int tm = 0; tm < 4; ++tm) {
        short8 afr = *(const short8*)(R1 + (tm * 16 + fm) * 72 + k0);
        acc[0][tm] = __builtin_amdgcn_mfma_f32_16x16x32_bf16(afr, bfr0, acc[0][tm], 0, 0, 0);
        acc[1][tm] = __builtin_amdgcn_mfma_f32_16x16x32_bf16(afr, bfr1, acc[1][tm], 0, 0, 0);
      }
    }
    #pragma unroll
    for (int tn = 0; tn < 2; ++tn) {
      int col = colbase + tn * 16 + fm;
      float pb2c = pb2[col];
      #pragma unroll
      for (int tm = 0; tm < 4; ++tm)
        #pragma unroll
        for (int r = 0; r < 4; ++r) {
          int row = tm * 16 + quad * 4 + r;
          float rpe = acc[tn][tm][r] + pb2c;
          u32 w = pvld[tn][tm][r];
          Xt[row * XT_LD + col] = f2bf(bf2f((u16)(w & 0xffffu)) + rpe);
          u32 vb = (u32)f2bf(bf2f((u16)(w >> 16)) + rpe);
          if (tn == 0) vp[tm][r] = vb; else vp[tm][r] |= vb << 16;
        }
    }
  }
  __syncthreads();

  // phase 3: S = relu(X@a1+ab1)@a2, 4 chunks of 128 hidden cols
  f32x4 accS[2][4];
  #pragma unroll
  for (int tn = 0; tn < 2; ++tn)
    #pragma unroll
    for (int tm = 0; tm < 4; ++tm) accS[tn][tm] = (f32x4){0.f, 0.f, 0.f, 0.f};
  #pragma unroll 1
  for (int c = 0; c < 4; ++c) {
    f32x4 acc1[2][4];
    #pragma unroll
    for (int tn = 0; tn < 2; ++tn)
      #pragma unroll
      for (int tm = 0; tm < 4; ++tm) acc1[tn][tm] = (f32x4){0.f, 0.f, 0.f, 0.f};
    #pragma unroll
    for (int ks = 0; ks < 4; ++ks) {
      int k0 = ks * 32 + quad * 8;
      short8 bfr0 = *(const short8*)(a1T + (c * 128 + colbase + fm) * 128 + k0);
      short8 bfr1 = *(const short8*)(a1T + (c * 128 + colbase + 16 + fm) * 128 + k0);
      #pragma unroll
      for (int tm = 0; tm < 4; ++tm) {
        short8 afr = *(const short8*)(Xt + (tm * 16 + fm) * XT_LD + k0);
        acc1[0][tm] = __builtin_amdgcn_mfma_f32_16x16x32_bf16(afr, bfr0, acc1[0][tm], 0, 0, 0);
        acc1[1][tm] = __builtin_amdgcn_mfma_f32_16x16x32_bf16(afr, bfr1, acc1[1][tm], 0, 0, 0);
      }
    }
    #pragma unroll
    for (int tn = 0; tn < 2; ++tn) {
      int lcol = colbase + tn * 16 + fm;
      float ab1c = ab1[c * 128 + lcol];
      #pragma unroll
      for (int tm = 0; tm < 4; ++tm)
        #pragma unroll
        for (int r = 0; r < 4; ++r) {
          int row = tm * 16 + quad * 4 + r;
          Hs[row * XT_LD + lcol] = f2bf(fmaxf(acc1[tn][tm][r] + ab1c, 0.0f));
        }
    }
    __syncthreads();
    #pragma unroll
    for (int ks = 0; ks < 4; ++ks) {
      int k0 = ks * 32 + quad * 8;
      short8 bfr0 = *(const short8*)(a2T + (colbase + fm) * AH + c * 128 + k0);
      short8 bfr1 = *(const short8*)(a2T + (colbase + 16 + fm) * AH + c * 128 + k0);
      #pragma unroll
      for (int tm = 0; tm < 4; ++tm) {
        short8 afr = *(const short8*)(Hs + (tm * 16 + fm) * XT_LD + k0);
        accS[0][tm] = __builtin_amdgcn_mfma_f32_16x16x32_bf16(afr, bfr0, accS[0][tm], 0, 0, 0);
        accS[1][tm] = __builtin_amdgcn_mfma_f32_16x16x32_bf16(afr, bfr1, accS[1][tm], 0, 0, 0);
      }
    }
    __syncthreads();
  }

  // phase 4: softmax over 128 features per row, register-resident.
  {
    float ab2c0 = ab2[colbase + fm];
    float ab2c1 = ab2[colbase + 16 + fm];
    float rm[4][4];
    #pragma unroll
    for (int tm = 0; tm < 4; ++tm)
      #pragma unroll
      for (int r = 0; r < 4; ++r) {
        accS[0][tm][r] += ab2c0;
        accS[1][tm][r] += ab2c1;
        rm[tm][r] = fmaxf(accS[0][tm][r], accS[1][tm][r]);
      }
    #pragma unroll
    for (int off = 1; off <= 8; off <<= 1)
      #pragma unroll
      for (int tm = 0; tm < 4; ++tm)
        #pragma unroll
        for (int r = 0; r < 4; ++r)
          rm[tm][r] = fmaxf(rm[tm][r], __shfl_xor(rm[tm][r], off));
    if (fm == 0) {
      #pragma unroll
      for (int tm = 0; tm < 4; ++tm)
        #pragma unroll
        for (int r = 0; r < 4; ++r)
          Red1[wave * 64 + tm * 16 + quad * 4 + r] = rm[tm][r];
    }
    __syncthreads();
    #pragma unroll
    for (int tm = 0; tm < 4; ++tm)
      #pragma unroll
      for (int r = 0; r < 4; ++r) {
        int row = tm * 16 + quad * 4 + r;
        float m = fmaxf(fmaxf(Red1[row], Red1[64 + row]),
                        fmaxf(Red1[128 + row], Red1[192 + row]));
        float e0 = __expf(accS[0][tm][r] - m);
        float e1 = __expf(accS[1][tm][r] - m);
        accS[0][tm][r] = e0;
        accS[1][tm][r] = e1;
        rm[tm][r] = e0 + e1;
      }
    #pragma unroll
    for (int off = 1; off <= 8; off <<= 1)
      #pragma unroll
      for (int tm = 0; tm < 4; ++tm)
        #pragma unroll
        for (int r = 0; r < 4; ++r)
          rm[tm][r] += __shfl_xor(rm[tm][r], off);
    if (fm == 0) {
      #pragma unroll
      for (int tm = 0; tm < 4; ++tm)
        #pragma unroll
        for (int r = 0; r < 4; ++r)
          Red2[wave * 64 + tm * 16 + quad * 4 + r] = rm[tm][r];
    }
    __syncthreads();
    #pragma unroll
    for (int tm = 0; tm < 4; ++tm)
      #pragma unroll
      for (int r = 0; r < 4; ++r) {
        int row = tm * 16 + quad * 4 + r;
        float sum = (Red2[row] + Red2[64 + row]) +
                    (Red2[128 + row] + Red2[192 + row]);
        float inv = 1.0f / sum;   // sum >= exp(0) = 1
        accS[0][tm][r] *= inv;
        accS[1][tm][r] *= inv;
      }
  }

  // phase 5: L2-norm over the 16 neighbors + aggregate, register-resident.
  #pragma unroll
  for (int tn = 0; tn < 2; ++tn)
    #pragma unroll
    for (int tm = 0; tm < 4; ++tm) {
      float ssq = 0.f, wav = 0.f;
      #pragma unroll
      for (int r = 0; r < 4; ++r) {
        float a = accS[tn][tm][r];
        u16 vb = (u16)(tn == 0 ? (vp[tm][r] & 0xffffu) : (vp[tm][r] >> 16));
        ssq = fmaf(a, a, ssq);
        wav = fmaf(a, bf2f(vb), wav);
      }
      ssq += __shfl_xor(ssq, 16); ssq += __shfl_xor(ssq, 32);
      wav += __shfl_xor(wav, 16); wav += __shfl_xor(wav, 32);
      if (quad == 0)
        Agg[tm * EMB + colbase + tn * 16 + fm] =
            wav / fmaxf(sqrtf(ssq), 1e-12f);
    }
  __syncthreads();

  // phase 7: out = Agg @ wo + bo
  {
    int d = tid & 127, qp = tid >> 7;
    float boc = bo[d];
    #pragma unroll
    for (int qi2 = 0; qi2 < 2; ++qi2) {
      int q = qp * 2 + qi2;
      float o = 0.f;
      #pragma unroll
      for (int k8 = 0; k8 < 16; ++k8) {
        short8 w8 = *(const short8*)(woT + d * 128 + k8 * 8);
        #pragma unroll
        for (int e = 0; e < 8; ++e)
          o = fmaf(Agg[q * EMB + k8 * 8 + e], bf2f((u16)w8[e]), o);
      }
      out[((size_t)b * NPT + qbase + q) * EMB + d] = o + boc;
    }
  }
}

// ---------------------------------------------------------------- launch
extern "C" void kernel_launch(void* const* d_in, const int* in_sizes, int n_in,
                              void* d_out, int out_size, void* d_ws, size_t ws_size,
                              hipStream_t stream) {
  (void)in_sizes; (void)n_in; (void)out_size; (void)ws_size;
  const float* query = (const float*)d_in[0];
  const float* key_i = (const float*)d_in[1];
  const float* value = (const float*)d_in[2];
  const float* can   = (const float*)d_in[3];
  const float* wq  = (const float*)d_in[4];
  const float* wk  = (const float*)d_in[5];
  const float* wv  = (const float*)d_in[6];
  const float* wo  = (const float*)d_in[7];
  const float* bo  = (const float*)d_in[8];
  const float* p1  = (const float*)d_in[9];
  const float* pb1 = (const float*)d_in[10];
  const float* p2  = (const float*)d_in[11];
  const float* pb2 = (const float*)d_in[12];
  const float* a1  = (const float*)d_in[13];
  const float* ab1 = (const float*)d_in[14];
  const float* a2  = (const float*)d_in[15];
  const float* ab2 = (const float*)d_in[16];

  char* ws = (char*)d_ws;
  u32* pv_ws = (u32*)(ws + 0);            // 4*2048*128 u32 = 4 MiB
  int* idx_ws  = (int*)(ws + 8388608);    // 512 KiB
  u16* wqT = (u16*)(ws + 8912896);
  u16* wkT = (u16*)(ws + 8945664);
  u16* wvT = (u16*)(ws + 8978432);
  u16* p2T = (u16*)(ws + 9011200);
  u16* a1T = (u16*)(ws + 9027584);
  u16* a2T = (u16*)(ws + 9158656);
  u16* woT = (u16*)(ws + 9289728);
  float* out = (float*)d_out;

  k_transpose<<<dim3(40), dim3(256), 0, stream>>>(
      wq, wk, wv, p2, a1, a2, wo, wqT, wkT, wvT, p2T, a1T, a2T, woT);
  k_fused<<<dim3(2304), dim3(256), 0, stream>>>(
      can, idx_ws, query, key_i, value, wqT, wkT, wvT, pv_ws);
  k_attn<<<dim3(2048), dim3(256), 0, stream>>>(
      can, pv_ws, idx_ws, p1, pb1, p2T, pb2, a1T, ab1, a2T, ab2,
      woT, bo, out);
}